// Round 2
// baseline (1800.919 us; speedup 1.0000x reference)
//
#include <hip/hip_runtime.h>
#include <math.h>

// ---- problem constants ----
#define NN 2000     // nodes
#define NB 16       // batch
#define NL 12       // seq len
#define NC 32       // channels
#define KW 6144     // NB*NL*NC   (H row width)
#define SW 384      // slab width NB*NL*2
#define LNCNT 768000.0f

// ---- workspace float offsets ----
#define O_ROWS  ((size_t)0)
#define O_COLS  ((size_t)2048)
#define O_LN    ((size_t)4096)        // 32 used (sum[16], sumsq[16])
#define O_CM    ((size_t)4224)        // 7*32*2 = 448
#define O_CV    ((size_t)4672)        // 32
#define O_M1    ((size_t)8192)                  // 4,000,000
#define O_M2    (O_M1 + (size_t)4000000)
#define O_T     (O_M2 + (size_t)4000000)
#define O_P1    (O_T  + (size_t)4000000)        // P1 then P2 contiguous -> stacked A
#define O_P2    (O_P1 + (size_t)4000000)
#define O_H     (O_P2 + (size_t)4000000)        // 12,288,000 floats
// T2 = M2^2 lives in the H region (dead until k_combine, by which time T2 is dead)
#define O_T2    O_H
// slabs overlay the (dead after square GEMMs) M1/M2/T region:
#define O_X     O_M1                            // 768,000   (2000 x 384)
#define O_YSTK  (O_X + (size_t)768000)          // 1,536,000 (4000 x 384) [Y1;Y2]
#define O_YSIDE (O_YSTK + (size_t)1536000)      // 1,536,000 (2000 x 768) [Y1|Y2]
#define O_ZSTK  (O_YSIDE + (size_t)1536000)     // 3,072,000 (4000 x 768) [[Y11|Y12];[Y21|Y22]]

__device__ __forceinline__ float blockReduceSum(float v, float* sbuf) {
  #pragma unroll
  for (int off = 32; off > 0; off >>= 1) v += __shfl_down(v, off, 64);
  int wid = threadIdx.x >> 6, lane = threadIdx.x & 63;
  if (lane == 0) sbuf[wid] = v;
  __syncthreads();
  v = (threadIdx.x < 4) ? sbuf[threadIdx.x] : 0.f;
  if (threadIdx.x < 64) { v += __shfl_down(v, 2, 64); v += __shfl_down(v, 1, 64); }
  return v;  // valid in thread 0
}

__global__ void k_rowsum(const float* __restrict__ adj, float* __restrict__ rows) {
  __shared__ float sb[4];
  int n = blockIdx.x;
  const float4* a4 = (const float4*)(adj + (size_t)n * NN);
  float s = 0.f;
  for (int t = threadIdx.x; t < NN / 4; t += 256) {
    float4 v = a4[t];
    s += v.x + v.y + v.z + v.w;
  }
  s = blockReduceSum(s, sb);
  if (threadIdx.x == 0) rows[n] = s + 1.0f;
}

__global__ void k_colsum(const float* __restrict__ adj, float* __restrict__ cols) {
  __shared__ float sb[4][64];
  int col = blockIdx.x * 64 + (threadIdx.x & 63);
  int rg = threadIdx.x >> 6;
  float s = 0.f;
  if (col < NN)
    for (int m = rg; m < NN; m += 4) s += adj[(size_t)m * NN + col];
  sb[rg][threadIdx.x & 63] = s;
  __syncthreads();
  if (rg == 0 && col < NN)
    cols[col] = sb[0][threadIdx.x] + sb[1][threadIdx.x] + sb[2][threadIdx.x] + sb[3][threadIdx.x] + 1.0f;
}

// M1 = 0.75 I + 0.25*(adj + I)/rowsum  ; M2 = 0.75 I + 0.25*(adj^T + I)/colsum
__global__ void k_buildM(const float* __restrict__ adj, const float* __restrict__ rows,
                         const float* __restrict__ cols, float* __restrict__ M1,
                         float* __restrict__ M2) {
  __shared__ float Ta[64][65];
  __shared__ float Tb[64][65];
  int r0 = blockIdx.y * 64, c0 = blockIdx.x * 64;
  for (int e = threadIdx.x; e < 4096; e += 256) {
    int i = e >> 6, j = e & 63;
    int rr = r0 + i, cc = c0 + j;
    Ta[i][j] = (rr < NN && cc < NN) ? adj[(size_t)rr * NN + cc] : 0.f;
    int rr2 = c0 + i, cc2 = r0 + j;
    Tb[i][j] = (rr2 < NN && cc2 < NN) ? adj[(size_t)rr2 * NN + cc2] : 0.f;
  }
  __syncthreads();
  for (int e = threadIdx.x; e < 4096; e += 256) {
    int i = e >> 6, j = e & 63;
    int n = r0 + i, m = c0 + j;
    if (n < NN && m < NN) {
      float d = (n == m) ? 1.f : 0.f;
      M1[(size_t)n * NN + m] = 0.75f * d + 0.25f * (Ta[i][j] + d) / rows[n];
      M2[(size_t)n * NN + m] = 0.75f * d + 0.25f * (Tb[j][i] + d) / cols[n];
    }
  }
}

// channel-space word matrices Cm[7][32][2] and the constant channel vector
__global__ void k_prep(const float* __restrict__ wS, const float* __restrict__ bS,
                       const float* __restrict__ G1, const float* __restrict__ bg1,
                       const float* __restrict__ G2, const float* __restrict__ bg2,
                       float* __restrict__ Cm, float* __restrict__ cvec) {
  __shared__ float A1[64], A2[64], u1[32], v2[32];
  int t = threadIdx.x;          // 64 threads
  int c = t >> 1, ci = t & 1;
  Cm[t] = wS[c * 2 + ci];       // w0 = S
  float a1 = 0.f, a2 = 0.f;
  for (int j = 0; j < 32; ++j) {
    a1 += G1[c * 32 + j] * wS[j * 2 + ci];
    a2 += G2[c * 32 + j] * wS[j * 2 + ci];
  }
  A1[t] = a1; A2[t] = a2;
  Cm[64 + t] = a1;              // w1 = G1 S
  Cm[128 + t] = a2;             // w2 = G2 S
  __syncthreads();
  float b11 = 0, b12 = 0, b21 = 0, b22 = 0;
  for (int j = 0; j < 32; ++j) {
    b11 += G1[c * 32 + j] * A1[j * 2 + ci];
    b12 += G1[c * 32 + j] * A2[j * 2 + ci];
    b21 += G2[c * 32 + j] * A1[j * 2 + ci];
    b22 += G2[c * 32 + j] * A2[j * 2 + ci];
  }
  Cm[192 + t] = 0.25f * b11;    // w11: 0.25 G1^2 S  (pairs P1^2 -> Z11)
  Cm[256 + t] = 0.25f * b12;    // w12: 0.25 G1G2 S  (pairs P1P2 -> Z12)
  Cm[320 + t] = 0.25f * b21;    // w21: 0.25 G2G1 S  (pairs P2P1 -> Z21)
  Cm[384 + t] = 0.25f * b22;    // w22: 0.25 G2^2 S  (pairs P2^2 -> Z22)
  if (t < 32) {
    float uu = 0.f, vv = 0.f;
    for (int j = 0; j < 32; ++j) {
      float F = G1[t * 32 + j] + G2[t * 32 + j];
      uu += F * bS[j];
      vv += F * (bg1[j] + bg2[j]);
    }
    u1[t] = uu; v2[t] = vv;
  }
  __syncthreads();
  if (t < 32) {
    float u2v = 0.f;
    for (int j = 0; j < 32; ++j)
      u2v += (G1[t * 32 + j] + G2[t * 32 + j]) * u1[j];
    // const = s + Fs + 0.25 F^2 s + (g1+g2) + 0.25 F (g1+g2)
    cvec[t] = bS[t] + u1[t] + 0.25f * u2v + (bg1[t] + bg2[t]) + 0.25f * v2[t];
  }
}

// C[M,N] = A[M,K] @ B[K,N], row-major fp32. BM=128, BK=16, BN templated.
// gridDim.z selects the (A,B,C) pointer set -> 2 independent GEMMs per launch.
template <int BN_>
__global__ __launch_bounds__(256) void sgemm_b2(
    const float* __restrict__ A_0, const float* __restrict__ B_0, float* __restrict__ C_0,
    const float* __restrict__ A_1, const float* __restrict__ B_1, float* __restrict__ C_1,
    int lda, int ldb, int ldc, int M, int N, int K) {
  const float* A = (blockIdx.z == 0) ? A_0 : A_1;
  const float* B = (blockIdx.z == 0) ? B_0 : B_1;
  float*       C = (blockIdx.z == 0) ? C_0 : C_1;
  const int TN = BN_ / 16;  // 8 or 4
  __shared__ float As[16][128 + 4];
  __shared__ float Bs[16][BN_ + 4];
  const int tid = threadIdx.x;
  const int row0 = blockIdx.y * 128;
  const int col0 = blockIdx.x * BN_;
  const int tm = (tid >> 4) << 3;
  const int tn = (tid & 15) * TN;
  float acc[8][TN];
  #pragma unroll
  for (int i = 0; i < 8; ++i)
    #pragma unroll
    for (int j = 0; j < TN; ++j) acc[i][j] = 0.f;

  for (int k0 = 0; k0 < K; k0 += 16) {
    #pragma unroll
    for (int i = 0; i < 2; ++i) {           // A tile 128x16 = 512 float4
      int t = tid + i * 256;
      int ar = t >> 2, ak = (t & 3) << 2;
      int gr = row0 + ar;
      float4 v = make_float4(0, 0, 0, 0);
      if (gr < M) v = *(const float4*)(A + (size_t)gr * lda + k0 + ak);
      As[ak + 0][ar] = v.x; As[ak + 1][ar] = v.y;
      As[ak + 2][ar] = v.z; As[ak + 3][ar] = v.w;
    }
    #pragma unroll
    for (int i = 0; i < BN_ / 64; ++i) {    // B tile 16xBN
      int t = tid + i * 256;
      int bk = t / (BN_ / 4);
      int bc = (t % (BN_ / 4)) << 2;
      int gc = col0 + bc;
      float4 v = make_float4(0, 0, 0, 0);
      if (gc < N) v = *(const float4*)(B + (size_t)(k0 + bk) * ldb + gc);
      *(float4*)(&Bs[bk][bc]) = v;
    }
    __syncthreads();
    #pragma unroll
    for (int kk = 0; kk < 16; ++kk) {
      float a[8], b[TN];
      *(float4*)(&a[0]) = *(const float4*)(&As[kk][tm]);
      *(float4*)(&a[4]) = *(const float4*)(&As[kk][tm + 4]);
      #pragma unroll
      for (int j4 = 0; j4 < TN / 4; ++j4)
        *(float4*)(&b[j4 * 4]) = *(const float4*)(&Bs[kk][tn + j4 * 4]);
      #pragma unroll
      for (int i = 0; i < 8; ++i)
        #pragma unroll
        for (int j = 0; j < TN; ++j) acc[i][j] += a[i] * b[j];
    }
    __syncthreads();
  }
  if (col0 + tn < N) {
    #pragma unroll
    for (int i = 0; i < 8; ++i) {
      int gr = row0 + tm + i;
      if (gr < M) {
        float* cp = C + (size_t)gr * ldc + col0 + tn;
        #pragma unroll
        for (int j = 0; j < TN; ++j) cp[j] = acc[i][j];
      }
    }
  }
}

// X[n, (b*12+l)*2 + ci] = x[b, l, n, ci]
__global__ void k_buildX(const float* __restrict__ xin, float* __restrict__ X) {
  int idx = blockIdx.x * 256 + threadIdx.x;
  if (idx >= NN * SW) return;
  int n = idx / SW, p = idx % SW;
  int bl = p >> 1, ci = p & 1;
  X[idx] = xin[((size_t)bl * NN + n) * 2 + ci];
}

// [4000x384] stacked -> [2000x768] side-by-side
__global__ void k_reshapeY(const float* __restrict__ Ystk, float* __restrict__ Yside) {
  int idx = blockIdx.x * 256 + threadIdx.x;
  if (idx >= NN * 768) return;
  int n = idx / 768, q = idx % 768;
  Yside[idx] = (q < 384) ? Ystk[(size_t)n * 384 + q]
                         : Ystk[(size_t)(NN + n) * 384 + (q - 384)];
}

// H[n, b*384 + l*32 + c] = cvec[c] + sum_w Cm[w][c][:] . slab_w[n, (b*12+l)*2 + :]
__global__ void k_combine(const float* __restrict__ X, const float* __restrict__ Ystk,
                          const float* __restrict__ Zstk, const float* __restrict__ Cm,
                          const float* __restrict__ cvec, float* __restrict__ H) {
  int idx = blockIdx.x * 256 + threadIdx.x;
  if (idx >= NN * KW) return;
  int n = idx / KW, j = idx % KW;
  int b = j / 384, r = j % 384;
  int l = r >> 5, c = r & 31;
  int p2 = (b * NL + l) * 2;
  int c2 = c * 2;
  size_t pX = (size_t)n * SW + p2;
  size_t pY2 = (size_t)(NN + n) * SW + p2;
  size_t pZ = (size_t)n * 768 + p2;
  size_t pZ2 = (size_t)(NN + n) * 768 + p2;
  float acc = cvec[c];
  acc += Cm[c2] * X[pX] + Cm[c2 + 1] * X[pX + 1];
  acc += Cm[64 + c2] * Ystk[pX] + Cm[64 + c2 + 1] * Ystk[pX + 1];
  acc += Cm[128 + c2] * Ystk[pY2] + Cm[128 + c2 + 1] * Ystk[pY2 + 1];
  acc += Cm[192 + c2] * Zstk[pZ] + Cm[192 + c2 + 1] * Zstk[pZ + 1];
  acc += Cm[256 + c2] * Zstk[pZ + 384] + Cm[256 + c2 + 1] * Zstk[pZ + 385];
  acc += Cm[320 + c2] * Zstk[pZ2] + Cm[320 + c2 + 1] * Zstk[pZ2 + 1];
  acc += Cm[384 + c2] * Zstk[pZ2 + 384] + Cm[384 + c2 + 1] * Zstk[pZ2 + 385];
  H[idx] = acc;
}

__global__ void k_lnreduce(const float* __restrict__ H, float* __restrict__ ln) {
  __shared__ float sb[4];
  int b = blockIdx.x & 15, chunk = blockIdx.x >> 4;
  int n0 = chunk * 125;
  float s = 0.f, ss = 0.f;
  for (int t = threadIdx.x; t < 125 * 96; t += 256) {
    int n = n0 + t / 96, q = t % 96;
    float4 v = *(const float4*)(H + (size_t)n * KW + b * 384 + q * 4);
    s += v.x + v.y + v.z + v.w;
    ss += v.x * v.x + v.y * v.y + v.z * v.z + v.w * v.w;
  }
  s = blockReduceSum(s, sb);
  __syncthreads();
  ss = blockReduceSum(ss, sb);
  if (threadIdx.x == 0) { atomicAdd(&ln[b], s); atomicAdd(&ln[16 + b], ss); }
}

__global__ __launch_bounds__(256) void k_epilogue(
    const float* __restrict__ H, const float* __restrict__ ln,
    const float* __restrict__ w0, const float* __restrict__ b0,
    const float* __restrict__ w1, const float* __restrict__ b1,
    const float* __restrict__ w2, const float* __restrict__ b2,
    float* __restrict__ out) {
  int p = blockIdx.x * 256 + threadIdx.x;  // b*(NL*NN) + l*NN + n
  if (p >= NB * NL * NN) return;
  int b = p / (NL * NN);
  int r = p % (NL * NN);
  int l = r / NN;
  int n = r % NN;
  float mu = ln[b] * (1.0f / LNCNT);
  float var = ln[16 + b] * (1.0f / LNCNT) - mu * mu;
  float rs = rsqrtf(fmaxf(var, 0.f) + 1e-5f);
  float x[32];
  const float* hp = H + (size_t)n * KW + b * 384 + l * 32;
  #pragma unroll
  for (int q = 0; q < 8; ++q) {
    float4 v = *(const float4*)(hp + q * 4);
    x[q * 4 + 0] = (v.x - mu) * rs;
    x[q * 4 + 1] = (v.y - mu) * rs;
    x[q * 4 + 2] = (v.z - mu) * rs;
    x[q * 4 + 3] = (v.w - mu) * rs;
  }
  float y0[64];
  #pragma unroll
  for (int o = 0; o < 64; ++o) {
    float acc = b0[o];
    const float* wr = w0 + o * 32;        // uniform address -> scalar loads
    #pragma unroll
    for (int i = 0; i < 32; ++i) acc += wr[i] * x[i];
    y0[o] = fmaxf(acc, 0.f);
  }
  float outv[12];
  #pragma unroll
  for (int o = 0; o < 12; ++o) outv[o] = b2[o];
  for (int jj = 0; jj < 128; ++jj) {
    float acc = b1[jj];
    const float* wr = w1 + jj * 64;       // uniform address -> scalar loads
    #pragma unroll
    for (int i = 0; i < 64; ++i) acc += wr[i] * y0[i];
    acc = fmaxf(acc, 0.f);
    #pragma unroll
    for (int o = 0; o < 12; ++o) outv[o] += w2[o * 128 + jj] * acc;
  }
  float* op = out + ((size_t)(b * NL + l) * NN + n) * 12;
  #pragma unroll
  for (int o = 0; o < 12; ++o) op[o] = outv[o];
}

extern "C" void kernel_launch(void* const* d_in, const int* in_sizes, int n_in,
                              void* d_out, int out_size, void* d_ws, size_t ws_size,
                              hipStream_t stream) {
  (void)in_sizes; (void)n_in; (void)out_size; (void)ws_size;
  const float* x   = (const float*)d_in[0];
  const float* adj = (const float*)d_in[1];
  const float* wS  = (const float*)d_in[2];
  const float* bS  = (const float*)d_in[3];
  const float* G1  = (const float*)d_in[4];
  const float* bg1 = (const float*)d_in[5];
  const float* G2  = (const float*)d_in[6];
  const float* bg2 = (const float*)d_in[7];
  const float* we0 = (const float*)d_in[8];
  const float* be0 = (const float*)d_in[9];
  const float* we1 = (const float*)d_in[10];
  const float* be1 = (const float*)d_in[11];
  const float* we2 = (const float*)d_in[12];
  const float* be2 = (const float*)d_in[13];
  float* out = (float*)d_out;
  float* wsf = (float*)d_ws;

  float* rows = wsf + O_ROWS;
  float* cols = wsf + O_COLS;
  float* lnb  = wsf + O_LN;
  float* Cm   = wsf + O_CM;
  float* cvec = wsf + O_CV;
  float* M1   = wsf + O_M1;
  float* M2   = wsf + O_M2;
  float* T1   = wsf + O_T;
  float* T2   = wsf + O_T2;   // overlays H region (dead until k_combine)
  float* P1   = wsf + O_P1;   // [P1;P2] contiguous -> stacked 4000x2000 A
  float* P2   = wsf + O_P2;
  float* H    = wsf + O_H;
  float* X    = wsf + O_X;
  float* Ystk = wsf + O_YSTK;
  float* Ysid = wsf + O_YSIDE;
  float* Zstk = wsf + O_ZSTK;

  hipMemsetAsync(lnb, 0, 32 * sizeof(float), stream);
  k_rowsum<<<NN, 256, 0, stream>>>(adj, rows);
  k_colsum<<<32, 256, 0, stream>>>(adj, cols);
  k_buildM<<<dim3(32, 32), 256, 0, stream>>>(adj, rows, cols, M1, M2);
  k_prep<<<1, 64, 0, stream>>>(wS, bS, G1, bg1, G2, bg2, Cm, cvec);

  // T1 = M1^2, T2 = M2^2   (one batched launch, 512 blocks)
  sgemm_b2<128><<<dim3(16, 16, 2), 256, 0, stream>>>(
      M1, M1, T1, M2, M2, T2, NN, NN, NN, NN, NN, NN);
  // P1 = T1^2, P2 = T2^2   (one batched launch, 512 blocks)
  sgemm_b2<128><<<dim3(16, 16, 2), 256, 0, stream>>>(
      T1, T1, P1, T2, T2, P2, NN, NN, NN, NN, NN, NN);

  // slabs (overlay M1/M2/T region — safe, M1/M2/T1 dead now; T2 in H region dead too)
  k_buildX<<<(NN * SW + 255) / 256, 256, 0, stream>>>(x, X);
  // [Y1;Y2] = [P1;P2] @ X   (4000 x 384)
  sgemm_b2<64><<<dim3(6, 32, 1), 256, 0, stream>>>(
      P1, X, Ystk, P1, X, Ystk, NN, SW, SW, 2 * NN, SW, NN);
  k_reshapeY<<<(NN * 768 + 255) / 256, 256, 0, stream>>>(Ystk, Ysid);
  // [[Z11|Z12];[Z21|Z22]] = [P1;P2] @ [Y1|Y2]   (4000 x 768)
  sgemm_b2<64><<<dim3(12, 32, 1), 256, 0, stream>>>(
      P1, Ysid, Zstk, P1, Ysid, Zstk, NN, 768, 768, 2 * NN, 768, NN);

  k_combine<<<(NN * KW + 255) / 256, 256, 0, stream>>>(X, Ystk, Zstk, Cm, cvec, H);
  k_lnreduce<<<256, 256, 0, stream>>>(H, lnb);
  k_epilogue<<<(NB * NL * NN + 255) / 256, 256, 0, stream>>>(
      H, lnb, we0, be0, we1, be1, we2, be2, out);
}

// Round 7
// 868.192 us; speedup vs baseline: 2.0743x; 2.0743x over previous
//
#include <hip/hip_runtime.h>
#include <math.h>

// ---- problem constants ----
#define NN 2000     // nodes
#define NP 2048     // padded nodes
#define NB 16
#define NL 12
#define KW 6144     // NB*NL*32
#define SW 384      // NB*NL*2
#define LNCNT 768000.0f

// ---- workspace float offsets ----
// small scalars
#define O_ROWS ((size_t)0)
#define O_COLS ((size_t)2048)
#define O_LN   ((size_t)4096)
#define O_CM   ((size_t)4224)
#define O_CV   ((size_t)4672)
// SZH = one 2048x2048 bf16 matrix, in float units
#define SZH ((size_t)2097152)
#define R1  ((size_t)8192)          // M1h,M1l,M2h,M2l  -> later Phi(2*SZH),Plo(2*SZH)
#define R2  (R1 + 4*SZH)            // M1Th,M1Tl,M2Th,M2Tl -> later T1Th,T1Tl,T2Th,T2Tl
#define R3  (R2 + 4*SZH)            // T1h,T1l,T2h,T2l -> later slabs
// slab offsets inside R3 (valid after GEMM2, T dead):
#define O_X   (R3 + 0)              // 768,000 f32  [2000][384]
#define O_XTH (R3 + 768000)         // 393,216 (384*2048 u16)
#define O_XTL (O_XTH + 393216)
#define O_YF  (O_XTL + 393216)      // 1,572,864 f32 [4096][384]
#define O_YTH (O_YF + 1572864)      // 786,432 (768*2048 u16)
#define O_YTL (O_YTH + 786432)
#define O_ZF  (O_YTL + 786432)      // 3,145,728 f32 [4096][768]
// H overlays R1(+part of R2): P dead by combine time. 12,288,000 f32 ends < R3.
#define O_H   R1

typedef __attribute__((ext_vector_type(8))) short short8;
typedef __attribute__((ext_vector_type(4))) float f32x4;

__device__ __forceinline__ unsigned short f2bf(float f) {
  union { float f; unsigned u; } x; x.f = f;
  unsigned r = x.u + 0x7fff + ((x.u >> 16) & 1);   // RNE
  return (unsigned short)(r >> 16);
}
__device__ __forceinline__ float bf2f(unsigned short b) {
  union { unsigned u; float f; } x; x.u = ((unsigned)b) << 16;
  return x.f;
}
__device__ __forceinline__ void gld16(const void* g, void* l) {
  __builtin_amdgcn_global_load_lds(
      (const __attribute__((address_space(1))) unsigned int*)g,
      (__attribute__((address_space(3))) unsigned int*)l, 16, 0, 0);
}

__device__ __forceinline__ float blockReduceSum(float v, float* sbuf) {
  #pragma unroll
  for (int off = 32; off > 0; off >>= 1) v += __shfl_down(v, off, 64);
  int wid = threadIdx.x >> 6, lane = threadIdx.x & 63;
  if (lane == 0) sbuf[wid] = v;
  __syncthreads();
  v = (threadIdx.x < 4) ? sbuf[threadIdx.x] : 0.f;
  if (threadIdx.x < 64) { v += __shfl_down(v, 2, 64); v += __shfl_down(v, 1, 64); }
  return v;
}

__global__ void k_rowsum(const float* __restrict__ adj, float* __restrict__ rows) {
  __shared__ float sb[4];
  int n = blockIdx.x;
  const float4* a4 = (const float4*)(adj + (size_t)n * NN);
  float s = 0.f;
  for (int t = threadIdx.x; t < NN / 4; t += 256) {
    float4 v = a4[t];
    s += v.x + v.y + v.z + v.w;
  }
  s = blockReduceSum(s, sb);
  if (threadIdx.x == 0) rows[n] = s + 1.0f;
}

__global__ void k_colsum(const float* __restrict__ adj, float* __restrict__ cols) {
  __shared__ float sb[4][64];
  int col = blockIdx.x * 64 + (threadIdx.x & 63);
  int rg = threadIdx.x >> 6;
  float s = 0.f;
  if (col < NN)
    for (int m = rg; m < NN; m += 4) s += adj[(size_t)m * NN + col];
  sb[rg][threadIdx.x & 63] = s;
  __syncthreads();
  if (rg == 0 && col < NN)
    cols[col] = sb[0][threadIdx.x] + sb[1][threadIdx.x] + sb[2][threadIdx.x] + sb[3][threadIdx.x] + 1.0f;
}

// Build split-bf16 M1, M2 AND their transposes, zero-padded to 2048x2048.
// M1 = 0.75 I + 0.25*(adj + I)/rowsum ; M2 = 0.75 I + 0.25*(adj^T + I)/colsum
__global__ void k_buildM8(const float* __restrict__ adj, const float* __restrict__ rows,
                          const float* __restrict__ cols,
                          unsigned short* __restrict__ M1h, unsigned short* __restrict__ M1l,
                          unsigned short* __restrict__ M2h, unsigned short* __restrict__ M2l,
                          unsigned short* __restrict__ M1Th, unsigned short* __restrict__ M1Tl,
                          unsigned short* __restrict__ M2Th, unsigned short* __restrict__ M2Tl) {
  __shared__ float Ta[64][65];
  __shared__ float Tb[64][65];
  int r0 = blockIdx.y * 64, c0 = blockIdx.x * 64;
  for (int e = threadIdx.x; e < 4096; e += 256) {
    int i = e >> 6, j = e & 63;
    int rr = r0 + i, cc = c0 + j;
    Ta[i][j] = (rr < NN && cc < NN) ? adj[(size_t)rr * NN + cc] : 0.f;
    int rr2 = c0 + i, cc2 = r0 + j;
    Tb[i][j] = (rr2 < NN && cc2 < NN) ? adj[(size_t)rr2 * NN + cc2] : 0.f;
  }
  __syncthreads();
  for (int e = threadIdx.x; e < 4096; e += 256) {
    int i = e >> 6, j = e & 63;
    int n = r0 + i, m = c0 + j;
    bool in = (n < NN && m < NN);
    float d = (n == m) ? 1.f : 0.f;
    float v1 = 0.f, v2 = 0.f, v1t = 0.f, v2t = 0.f;
    if (in) {
      v1  = 0.75f * d + 0.25f * (Ta[i][j] + d) / rows[n];   // M1[n][m]
      v2  = 0.75f * d + 0.25f * (Tb[j][i] + d) / cols[n];   // M2[n][m]
      v1t = 0.75f * d + 0.25f * (Tb[j][i] + d) / rows[m];   // M1[m][n]
      v2t = 0.75f * d + 0.25f * (Ta[i][j] + d) / cols[m];   // M2[m][n]
    }
    size_t o = (size_t)n * NP + m;
    unsigned short h;
    h = f2bf(v1);  M1h[o]  = h; M1l[o]  = f2bf(v1  - bf2f(h));
    h = f2bf(v2);  M2h[o]  = h; M2l[o]  = f2bf(v2  - bf2f(h));
    h = f2bf(v1t); M1Th[o] = h; M1Tl[o] = f2bf(v1t - bf2f(h));
    h = f2bf(v2t); M2Th[o] = h; M2Tl[o] = f2bf(v2t - bf2f(h));
  }
}

// channel-space word matrices Cm[7][32][2] and the constant channel vector
__global__ void k_prep(const float* __restrict__ wS, const float* __restrict__ bS,
                       const float* __restrict__ G1, const float* __restrict__ bg1,
                       const float* __restrict__ G2, const float* __restrict__ bg2,
                       float* __restrict__ Cm, float* __restrict__ cvec) {
  __shared__ float A1[64], A2[64], u1[32], v2[32];
  int t = threadIdx.x;          // 64 threads
  int c = t >> 1, ci = t & 1;
  Cm[t] = wS[c * 2 + ci];       // w0 = S
  float a1 = 0.f, a2 = 0.f;
  for (int j = 0; j < 32; ++j) {
    a1 += G1[c * 32 + j] * wS[j * 2 + ci];
    a2 += G2[c * 32 + j] * wS[j * 2 + ci];
  }
  A1[t] = a1; A2[t] = a2;
  Cm[64 + t] = a1;              // w1 = G1 S
  Cm[128 + t] = a2;             // w2 = G2 S
  __syncthreads();
  float b11 = 0, b12 = 0, b21 = 0, b22 = 0;
  for (int j = 0; j < 32; ++j) {
    b11 += G1[c * 32 + j] * A1[j * 2 + ci];
    b12 += G1[c * 32 + j] * A2[j * 2 + ci];
    b21 += G2[c * 32 + j] * A1[j * 2 + ci];
    b22 += G2[c * 32 + j] * A2[j * 2 + ci];
  }
  Cm[192 + t] = 0.25f * b11;    // pairs P1Y1 (Z11)
  Cm[256 + t] = 0.25f * b12;    // pairs P1Y2 (Z12)
  Cm[320 + t] = 0.25f * b21;    // pairs P2Y1 (Z21)
  Cm[384 + t] = 0.25f * b22;    // pairs P2Y2 (Z22)
  if (t < 32) {
    float uu = 0.f, vv = 0.f;
    for (int j = 0; j < 32; ++j) {
      float F = G1[t * 32 + j] + G2[t * 32 + j];
      uu += F * bS[j];
      vv += F * (bg1[j] + bg2[j]);
    }
    u1[t] = uu; v2[t] = vv;
  }
  __syncthreads();
  if (t < 32) {
    float u2v = 0.f;
    for (int j = 0; j < 32; ++j)
      u2v += (G1[t * 32 + j] + G2[t * 32 + j]) * u1[j];
    cvec[t] = bS[t] + u1[t] + 0.25f * u2v + (bg1[t] + bg2[t]) + 0.25f * v2[t];
  }
}

// ---- split-bf16 MFMA GEMM, NT-form ----
// C[M,N] = A@B. A given row-major [M][K] as (ah,al); B given TRANSPOSED
// row-major [N][K] as (bh,bl). 3-term: ah*bh + ah*bl + al*bh.
// BM=128, BK=32, 256 threads = 4 waves (2x2), per-wave 64 x BN_/2 tile.
// M,N multiples of tile; K multiple of 32 (all dims pre-padded -> no guards).
struct MG {
  const unsigned short *ah, *al, *bh, *bl;
  unsigned short *ch, *cl;      // split output (OUTF32=0)
  float *cf;                    // f32 output  (OUTF32=1)
};

template <int BN_, int OUTF32>
__global__ __launch_bounds__(256) void mgemm(MG g0, MG g1, int lda, int ldb,
                                             int ldc, int K) {
  MG g = (blockIdx.z == 0) ? g0 : g1;
  __shared__ __align__(16) unsigned short sAh[128 * 32];
  __shared__ __align__(16) unsigned short sAl[128 * 32];
  __shared__ __align__(16) unsigned short sBh[BN_ * 32];
  __shared__ __align__(16) unsigned short sBl[BN_ * 32];
  const int tid = threadIdx.x;
  const int wid = tid >> 6, lane = tid & 63;
  const int row0 = blockIdx.y * 128, col0 = blockIdx.x * BN_;
  const int FN = BN_ / 32;            // frags per wave in N (128->4, 64->2)
  const int wr = (wid >> 1) * 64;
  const int wc = (wid & 1) * (BN_ / 2);
  const int lr = lane & 15;
  const int lk = (lane >> 4) * 8;
  const int r16 = lane >> 2;          // staging: row within 16-row chunk
  const int k16 = (lane & 3) * 8;     // staging: element offset within row
  const int BCH = BN_ / 16;           // B chunks per matrix
  const int CPW = (16 + 2 * BCH) / 4; // chunks per wave (8 or 6)

  f32x4 acc[4][FN];
  #pragma unroll
  for (int m = 0; m < 4; ++m)
    #pragma unroll
    for (int n = 0; n < FN; ++n) acc[m][n] = {0.f, 0.f, 0.f, 0.f};

  for (int k0 = 0; k0 < K; k0 += 32) {
    #pragma unroll
    for (int c = 0; c < CPW; ++c) {
      int gch = wid * CPW + c;
      const unsigned short* src;
      unsigned short* dst;
      if (gch < 16) {
        int q = gch & 7;
        src = (gch < 8 ? g.ah : g.al) + (size_t)(row0 + q * 16 + r16) * lda + k0 + k16;
        dst = (gch < 8 ? sAh : sAl) + q * 512;
      } else {
        int gb = gch - 16;
        int q = (gb < BCH) ? gb : gb - BCH;
        src = (gb < BCH ? g.bh : g.bl) + (size_t)(col0 + q * 16 + r16) * ldb + k0 + k16;
        dst = (gb < BCH ? sBh : sBl) + q * 512;
      }
      gld16(src, dst);
    }
    __syncthreads();    // compiler drains vmcnt before barrier -> LDS valid
    short8 ahf[4], alf[4], bhf[FN], blf[FN];
    #pragma unroll
    for (int m = 0; m < 4; ++m) {
      ahf[m] = *(const short8*)&sAh[(wr + m * 16 + lr) * 32 + lk];
      alf[m] = *(const short8*)&sAl[(wr + m * 16 + lr) * 32 + lk];
    }
    #pragma unroll
    for (int n = 0; n < FN; ++n) {
      bhf[n] = *(const short8*)&sBh[(wc + n * 16 + lr) * 32 + lk];
      blf[n] = *(const short8*)&sBl[(wc + n * 16 + lr) * 32 + lk];
    }
    #pragma unroll
    for (int m = 0; m < 4; ++m)
      #pragma unroll
      for (int n = 0; n < FN; ++n) {
        acc[m][n] = __builtin_amdgcn_mfma_f32_16x16x32_bf16(ahf[m], bhf[n], acc[m][n], 0, 0, 0);
        acc[m][n] = __builtin_amdgcn_mfma_f32_16x16x32_bf16(ahf[m], blf[n], acc[m][n], 0, 0, 0);
        acc[m][n] = __builtin_amdgcn_mfma_f32_16x16x32_bf16(alf[m], bhf[n], acc[m][n], 0, 0, 0);
      }
    __syncthreads();
  }
  // epilogue: C layout col=lane&15, row=(lane>>4)*4+r  [m89-verified]
  #pragma unroll
  for (int m = 0; m < 4; ++m)
    #pragma unroll
    for (int n = 0; n < FN; ++n)
      #pragma unroll
      for (int r = 0; r < 4; ++r) {
        int row = row0 + wr + m * 16 + (lane >> 4) * 4 + r;
        int col = col0 + wc + n * 16 + lr;
        float v = acc[m][n][r];
        if (OUTF32) {
          g.cf[(size_t)row * ldc + col] = v;
        } else {
          unsigned short h = f2bf(v);
          g.ch[(size_t)row * ldc + col] = h;
          g.cl[(size_t)row * ldc + col] = f2bf(v - bf2f(h));
        }
      }
}

// 2048x2048 bf16 transpose, z selects matrix (4 matrices)
__global__ void k_transpose(const unsigned short* __restrict__ S,
                            unsigned short* __restrict__ D) {
  const unsigned short* src = S + (size_t)blockIdx.z * 4194304;
  unsigned short* dst = D + (size_t)blockIdx.z * 4194304;
  __shared__ unsigned short t[64][72];
  int bx = blockIdx.x * 64, by = blockIdx.y * 64;
  int tid = threadIdx.x;
  int i0 = tid >> 4, j0 = (tid & 15) * 4;
  #pragma unroll
  for (int p = 0; p < 4; ++p) {
    int i = i0 + p * 16;
    ushort4 v = *(const ushort4*)&src[(size_t)(by + i) * NP + bx + j0];
    t[j0 + 0][i] = v.x; t[j0 + 1][i] = v.y; t[j0 + 2][i] = v.z; t[j0 + 3][i] = v.w;
  }
  __syncthreads();
  #pragma unroll
  for (int p = 0; p < 4; ++p) {
    int i = i0 + p * 16;
    ushort4 v;
    v.x = t[i][j0]; v.y = t[i][j0 + 1]; v.z = t[i][j0 + 2]; v.w = t[i][j0 + 3];
    *(ushort4*)&dst[(size_t)(bx + i) * NP + by + j0] = v;
  }
}

// X[n][p] fp32 (2000x384): X[n, (b*12+l)*2+ci] = x[b,l,n,ci]
__global__ void k_buildX(const float* __restrict__ xin, float* __restrict__ X) {
  int idx = blockIdx.x * 256 + threadIdx.x;
  if (idx >= NN * SW) return;
  int n = idx / SW, p = idx % SW;
  int bl = p >> 1, ci = p & 1;
  X[idx] = xin[((size_t)bl * NN + n) * 2 + ci];
}

// XT[q][n] split bf16 [384][2048], zero-padded
__global__ void k_buildXT(const float* __restrict__ xin,
                          unsigned short* __restrict__ XTh,
                          unsigned short* __restrict__ XTl) {
  int idx = blockIdx.x * 256 + threadIdx.x;
  if (idx >= SW * NP) return;
  int q = idx >> 11, n = idx & (NP - 1);
  float v = 0.f;
  if (n < NN) {
    int bl = q >> 1, ci = q & 1;
    v = xin[((size_t)bl * NN + n) * 2 + ci];
  }
  unsigned short h = f2bf(v);
  XTh[idx] = h; XTl[idx] = f2bf(v - bf2f(h));
}

// YT[q][n] split bf16 [768][2048]: YT[q][n] = Yf[n + (q>=384)*2048][q%384]
__global__ void k_reshapeYT(const float* __restrict__ Yf,
                            unsigned short* __restrict__ YTh,
                            unsigned short* __restrict__ YTl) {
  __shared__ float t[64][65];
  int q0 = blockIdx.x * 64;              // 12 blocks
  int n0 = blockIdx.y * 64;              // 32 blocks
  int half = (q0 >= 384) ? 2048 : 0;
  int qs = (q0 >= 384) ? q0 - 384 : q0;
  int tid = threadIdx.x;
  int i0 = tid >> 4, j0 = (tid & 15) * 4;
  #pragma unroll
  for (int p = 0; p < 4; ++p) {
    int i = i0 + p * 16;
    float4 v = *(const float4*)&Yf[(size_t)(half + n0 + i) * SW + qs + j0];
    t[j0 + 0][i] = v.x; t[j0 + 1][i] = v.y; t[j0 + 2][i] = v.z; t[j0 + 3][i] = v.w;
  }
  __syncthreads();
  #pragma unroll
  for (int p = 0; p < 4; ++p) {
    int i = i0 + p * 16;          // q offset
    #pragma unroll
    for (int j = 0; j < 4; ++j) {
      float v = t[i][j0 + j];
      size_t o = (size_t)(q0 + i) * NP + n0 + j0 + j;
      unsigned short h = f2bf(v);
      YTh[o] = h; YTl[o] = f2bf(v - bf2f(h));
    }
  }
}

// H[n, b*384+l*32+c] = cvec[c] + sum_w Cm[w][c][:] . slab_w
__global__ void k_combine(const float* __restrict__ X, const float* __restrict__ Yf,
                          const float* __restrict__ Zf, const float* __restrict__ Cm,
                          const float* __restrict__ cvec, float* __restrict__ H) {
  int idx = blockIdx.x * 256 + threadIdx.x;
  if (idx >= NN * KW) return;
  int n = idx / KW, j = idx % KW;
  int b = j / 384, r = j % 384;
  int l = r >> 5, c = r & 31;
  int p2 = (b * NL + l) * 2;
  int c2 = c * 2;
  size_t pX  = (size_t)n * SW + p2;
  size_t pY2 = (size_t)(2048 + n) * SW + p2;
  size_t pZ1 = (size_t)n * 768 + p2;
  size_t pZ2 = (size_t)(2048 + n) * 768 + p2;
  float acc = cvec[c];
  acc += Cm[c2] * X[pX] + Cm[c2 + 1] * X[pX + 1];
  acc += Cm[64 + c2] * Yf[pX] + Cm[64 + c2 + 1] * Yf[pX + 1];
  acc += Cm[128 + c2] * Yf[pY2] + Cm[128 + c2 + 1] * Yf[pY2 + 1];
  acc += Cm[192 + c2] * Zf[pZ1] + Cm[192 + c2 + 1] * Zf[pZ1 + 1];
  acc += Cm[256 + c2] * Zf[pZ1 + 384] + Cm[256 + c2 + 1] * Zf[pZ1 + 385];
  acc += Cm[320 + c2] * Zf[pZ2] + Cm[320 + c2 + 1] * Zf[pZ2 + 1];
  acc += Cm[384 + c2] * Zf[pZ2 + 384] + Cm[384 + c2 + 1] * Zf[pZ2 + 385];
  H[idx] = acc;
}

__global__ void k_lnreduce(const float* __restrict__ H, float* __restrict__ ln) {
  __shared__ float sb[4];
  int b = blockIdx.x & 15, chunk = blockIdx.x >> 4;
  int n0 = chunk * 125;
  float s = 0.f, ss = 0.f;
  for (int t = threadIdx.x; t < 125 * 96; t += 256) {
    int n = n0 + t / 96, q = t % 96;
    float4 v = *(const float4*)(H + (size_t)n * KW + b * 384 + q * 4);
    s += v.x + v.y + v.z + v.w;
    ss += v.x * v.x + v.y * v.y + v.z * v.z + v.w * v.w;
  }
  s = blockReduceSum(s, sb);
  __syncthreads();
  ss = blockReduceSum(ss, sb);
  if (threadIdx.x == 0) { atomicAdd(&ln[b], s); atomicAdd(&ln[16 + b], ss); }
}

__global__ __launch_bounds__(256) void k_epilogue(
    const float* __restrict__ H, const float* __restrict__ ln,
    const float* __restrict__ w0, const float* __restrict__ b0,
    const float* __restrict__ w1, const float* __restrict__ b1,
    const float* __restrict__ w2, const float* __restrict__ b2,
    float* __restrict__ out) {
  int p = blockIdx.x * 256 + threadIdx.x;
  if (p >= NB * NL * NN) return;
  int b = p / (NL * NN);
  int r = p % (NL * NN);
  int l = r / NN;
  int n = r % NN;
  float mu = ln[b] * (1.0f / LNCNT);
  float var = ln[16 + b] * (1.0f / LNCNT) - mu * mu;
  float rs = rsqrtf(fmaxf(var, 0.f) + 1e-5f);
  float x[32];
  const float* hp = H + (size_t)n * KW + b * 384 + l * 32;
  #pragma unroll
  for (int q = 0; q < 8; ++q) {
    float4 v = *(const float4*)(hp + q * 4);
    x[q * 4 + 0] = (v.x - mu) * rs;
    x[q * 4 + 1] = (v.y - mu) * rs;
    x[q * 4 + 2] = (v.z - mu) * rs;
    x[q * 4 + 3] = (v.w - mu) * rs;
  }
  float y0[64];
  #pragma unroll
  for (int o = 0; o < 64; ++o) {
    float acc = b0[o];
    const float* wr = w0 + o * 32;
    #pragma unroll
    for (int i = 0; i < 32; ++i) acc += wr[i] * x[i];
    y0[o] = fmaxf(acc, 0.f);
  }
  float outv[12];
  #pragma unroll
  for (int o = 0; o < 12; ++o) outv[o] = b2[o];
  for (int jj = 0; jj < 128; ++jj) {
    float acc = b1[jj];
    const float* wr = w1 + jj * 64;
    #pragma unroll
    for (int i = 0; i < 64; ++i) acc += wr[i] * y0[i];
    acc = fmaxf(acc, 0.f);
    #pragma unroll
    for (int o = 0; o < 12; ++o) outv[o] += w2[o * 128 + jj] * acc;
  }
  float* op = out + ((size_t)(b * NL + l) * NN + n) * 12;
  #pragma unroll
  for (int o = 0; o < 12; ++o) op[o] = outv[o];
}

extern "C" void kernel_launch(void* const* d_in, const int* in_sizes, int n_in,
                              void* d_out, int out_size, void* d_ws, size_t ws_size,
                              hipStream_t stream) {
  (void)in_sizes; (void)n_in; (void)out_size; (void)ws_size;
  const float* x   = (const float*)d_in[0];
  const float* adj = (const float*)d_in[1];
  const float* wS  = (const float*)d_in[2];
  const float* bS  = (const float*)d_in[3];
  const float* G1  = (const float*)d_in[4];
  const float* bg1 = (const float*)d_in[5];
  const float* G2  = (const float*)d_in[6];
  const float* bg2 = (const float*)d_in[7];
  const float* we0 = (const float*)d_in[8];
  const float* be0 = (const float*)d_in[9];
  const float* we1 = (const float*)d_in[10];
  const float* be1 = (const float*)d_in[11];
  const float* we2 = (const float*)d_in[12];
  const float* be2 = (const float*)d_in[13];
  float* out = (float*)d_out;
  float* wsf = (float*)d_ws;

  float* rows = wsf + O_ROWS;
  float* cols = wsf + O_COLS;
  float* lnb  = wsf + O_LN;
  float* Cm   = wsf + O_CM;
  float* cvec = wsf + O_CV;

  unsigned short* M1h  = (unsigned short*)(wsf + R1);
  unsigned short* M1l  = (unsigned short*)(wsf + R1 + SZH);
  unsigned short* M2h  = (unsigned short*)(wsf + R1 + 2 * SZH);
  unsigned short* M2l  = (unsigned short*)(wsf + R1 + 3 * SZH);
  unsigned short* M1Th = (unsigned short*)(wsf + R2);
  unsigned short* M1Tl = (unsigned short*)(wsf + R2 + SZH);
  unsigned short* M2Th = (unsigned short*)(wsf + R2 + 2 * SZH);
  unsigned short* M2Tl = (unsigned short*)(wsf + R2 + 3 * SZH);
  unsigned short* T1h  = (unsigned short*)(wsf + R3);
  unsigned short* T1l  = (unsigned short*)(wsf + R3 + SZH);
  unsigned short* T2h  = (unsigned short*)(wsf + R3 + 2 * SZH);
  unsigned short* T2l  = (unsigned short*)(wsf + R3 + 3 * SZH);
  // T^T overlays R2 (M^T dead after GEMM1)
  unsigned short* T1Th = M1Th;
  unsigned short* T1Tl = M1Tl;
  unsigned short* T2Th = M2Th;
  unsigned short* T2Tl = M2Tl;
  // P overlays R1 (M dead after GEMM1): stacked [P1;P2] 4096x2048
  unsigned short* Phi  = (unsigned short*)(wsf + R1);
  unsigned short* Plo  = (unsigned short*)(wsf + R1 + 2 * SZH);
  // slabs overlay R3 (T dead after GEMM2)
  float* X   = wsf + O_X;
  unsigned short* XTh = (unsigned short*)(wsf + O_XTH);
  unsigned short* XTl = (unsigned short*)(wsf + O_XTL);
  float* Yf  = wsf + O_YF;
  unsigned short* YTh = (unsigned short*)(wsf + O_YTH);
  unsigned short* YTl = (unsigned short*)(wsf + O_YTL);
  float* Zf  = wsf + O_ZF;
  float* H   = wsf + O_H;   // overlays R1/R2 (P, TT dead by combine)

  hipMemsetAsync(lnb, 0, 32 * sizeof(float), stream);
  k_rowsum<<<NN, 256, 0, stream>>>(adj, rows);
  k_colsum<<<32, 256, 0, stream>>>(adj, cols);
  k_buildM8<<<dim3(32, 32), 256, 0, stream>>>(adj, rows, cols,
      M1h, M1l, M2h, M2l, M1Th, M1Tl, M2Th, M2Tl);
  k_prep<<<1, 64, 0, stream>>>(wS, bS, G1, bg1, G2, bg2, Cm, cvec);

  // GEMM1: T1 = M1@M1, T2 = M2@M2  (split out)
  {
    MG a0 = {M1h, M1l, M1Th, M1Tl, T1h, T1l, nullptr};
    MG a1 = {M2h, M2l, M2Th, M2Tl, T2h, T2l, nullptr};
    mgemm<128, 0><<<dim3(16, 16, 2), 256, 0, stream>>>(a0, a1, NP, NP, NP, NP);
  }
  // T^T (4 matrices)
  k_transpose<<<dim3(32, 32, 4), 256, 0, stream>>>(T1h, T1Th);
  // GEMM2: P1 = T1@T1, P2 = T2@T2 -> stacked [P1;P2]
  {
    MG b0 = {T1h, T1l, T1Th, T1Tl, Phi, Plo, nullptr};
    MG b1 = {T2h, T2l, T2Th, T2Tl, Phi + (size_t)NP * NP, Plo + (size_t)NP * NP, nullptr};
    mgemm<128, 0><<<dim3(16, 16, 2), 256, 0, stream>>>(b0, b1, NP, NP, NP, NP);
  }
  // slabs
  k_buildX<<<(NN * SW + 255) / 256, 256, 0, stream>>>(x, X);
  k_buildXT<<<(SW * NP + 255) / 256, 256, 0, stream>>>(x, XTh, XTl);
  // GEMM3: Yf = [P1;P2] @ X   (4096 x 384, f32 out)
  {
    MG c0 = {Phi, Plo, XTh, XTl, nullptr, nullptr, Yf};
    mgemm<64, 1><<<dim3(6, 32, 1), 256, 0, stream>>>(c0, c0, NP, NP, SW, NP);
  }
  k_reshapeYT<<<dim3(12, 32), 256, 0, stream>>>(Yf, YTh, YTl);
  // GEMM4: Zf = [P1;P2] @ [Y1|Y2]  (4096 x 768, f32 out)
  {
    MG e0 = {Phi, Plo, YTh, YTl, nullptr, nullptr, Zf};
    mgemm<64, 1><<<dim3(12, 32, 1), 256, 0, stream>>>(e0, e0, NP, NP, 768, NP);
  }

  k_combine<<<(NN * KW + 255) / 256, 256, 0, stream>>>(X, Yf, Zf, Cm, cvec, H);
  k_lnreduce<<<256, 256, 0, stream>>>(H, lnb);
  k_epilogue<<<(NB * NL * NN + 255) / 256, 256, 0, stream>>>(
      H, lnb, we0, be0, we1, be1, we2, be2, out);
}

// Round 8
// 862.647 us; speedup vs baseline: 2.0877x; 1.0064x over previous
//
#include <hip/hip_runtime.h>
#include <math.h>

// ---- problem constants ----
#define NN 2000     // nodes
#define NP 2048     // padded nodes
#define NB 16
#define NL 12
#define KW 6144     // NB*NL*32
#define SW 384      // NB*NL*2
#define LNCNT 768000.0f

// ---- workspace float offsets ----
// small scalars
#define O_ROWS ((size_t)0)
#define O_COLS ((size_t)2048)
#define O_LN   ((size_t)4096)
#define O_CM   ((size_t)4224)
#define O_CV   ((size_t)4672)
// SZH = one 2048x2048 bf16 matrix, in float units
#define SZH ((size_t)2097152)
#define R1  ((size_t)8192)          // M1h,M1l,M2h,M2l  -> later Phi(2*SZH),Plo(2*SZH)
#define R2  (R1 + 4*SZH)            // M1Th,M1Tl,M2Th,M2Tl -> later T1Th,T1Tl,T2Th,T2Tl
#define R3  (R2 + 4*SZH)            // T1h,T1l,T2h,T2l -> later slabs
// slab offsets inside R3 (valid after GEMM2, T dead):
#define O_X   (R3 + 0)              // 768,000 f32  [2000][384]
#define O_XTH (R3 + 768000)         // 393,216 (384*2048 u16)
#define O_XTL (O_XTH + 393216)
#define O_YF  (O_XTL + 393216)      // 1,572,864 f32 [4096][384]
#define O_YTH (O_YF + 1572864)      // 786,432 (768*2048 u16)
#define O_YTL (O_YTH + 786432)
#define O_ZF  (O_YTL + 786432)      // 3,145,728 f32 [4096][768]
// H overlays R1(+part of R2): P dead by combine time. 12,288,000 f32 ends < R3.
#define O_H   R1

typedef __attribute__((ext_vector_type(8))) short short8;
typedef __attribute__((ext_vector_type(4))) float f32x4;

__device__ __forceinline__ unsigned short f2bf(float f) {
  union { float f; unsigned u; } x; x.f = f;
  unsigned r = x.u + 0x7fff + ((x.u >> 16) & 1);   // RNE
  return (unsigned short)(r >> 16);
}
__device__ __forceinline__ float bf2f(unsigned short b) {
  union { unsigned u; float f; } x; x.u = ((unsigned)b) << 16;
  return x.f;
}
__device__ __forceinline__ void gld16(const void* g, void* l) {
  __builtin_amdgcn_global_load_lds(
      (const __attribute__((address_space(1))) unsigned int*)g,
      (__attribute__((address_space(3))) unsigned int*)l, 16, 0, 0);
}

__device__ __forceinline__ float blockReduceSum(float v, float* sbuf) {
  #pragma unroll
  for (int off = 32; off > 0; off >>= 1) v += __shfl_down(v, off, 64);
  int wid = threadIdx.x >> 6, lane = threadIdx.x & 63;
  if (lane == 0) sbuf[wid] = v;
  __syncthreads();
  v = (threadIdx.x < 4) ? sbuf[threadIdx.x] : 0.f;
  if (threadIdx.x < 64) { v += __shfl_down(v, 2, 64); v += __shfl_down(v, 1, 64); }
  return v;
}

__global__ void k_rowsum(const float* __restrict__ adj, float* __restrict__ rows) {
  __shared__ float sb[4];
  int n = blockIdx.x;
  const float4* a4 = (const float4*)(adj + (size_t)n * NN);
  float s = 0.f;
  for (int t = threadIdx.x; t < NN / 4; t += 256) {
    float4 v = a4[t];
    s += v.x + v.y + v.z + v.w;
  }
  s = blockReduceSum(s, sb);
  if (threadIdx.x == 0) rows[n] = s + 1.0f;
}

__global__ void k_colsum(const float* __restrict__ adj, float* __restrict__ cols) {
  __shared__ float sb[4][64];
  int col = blockIdx.x * 64 + (threadIdx.x & 63);
  int rg = threadIdx.x >> 6;
  float s = 0.f;
  if (col < NN)
    for (int m = rg; m < NN; m += 4) s += adj[(size_t)m * NN + col];
  sb[rg][threadIdx.x & 63] = s;
  __syncthreads();
  if (rg == 0 && col < NN)
    cols[col] = sb[0][threadIdx.x] + sb[1][threadIdx.x] + sb[2][threadIdx.x] + sb[3][threadIdx.x] + 1.0f;
}

// Build split-bf16 M1, M2 AND their transposes, zero-padded to 2048x2048.
// M1 = 0.75 I + 0.25*(adj + I)/rowsum ; M2 = 0.75 I + 0.25*(adj^T + I)/colsum
__global__ void k_buildM8(const float* __restrict__ adj, const float* __restrict__ rows,
                          const float* __restrict__ cols,
                          unsigned short* __restrict__ M1h, unsigned short* __restrict__ M1l,
                          unsigned short* __restrict__ M2h, unsigned short* __restrict__ M2l,
                          unsigned short* __restrict__ M1Th, unsigned short* __restrict__ M1Tl,
                          unsigned short* __restrict__ M2Th, unsigned short* __restrict__ M2Tl) {
  __shared__ float Ta[64][65];
  __shared__ float Tb[64][65];
  int r0 = blockIdx.y * 64, c0 = blockIdx.x * 64;
  for (int e = threadIdx.x; e < 4096; e += 256) {
    int i = e >> 6, j = e & 63;
    int rr = r0 + i, cc = c0 + j;
    Ta[i][j] = (rr < NN && cc < NN) ? adj[(size_t)rr * NN + cc] : 0.f;
    int rr2 = c0 + i, cc2 = r0 + j;
    Tb[i][j] = (rr2 < NN && cc2 < NN) ? adj[(size_t)rr2 * NN + cc2] : 0.f;
  }
  __syncthreads();
  for (int e = threadIdx.x; e < 4096; e += 256) {
    int i = e >> 6, j = e & 63;
    int n = r0 + i, m = c0 + j;
    bool in = (n < NN && m < NN);
    float d = (n == m) ? 1.f : 0.f;
    float v1 = 0.f, v2 = 0.f, v1t = 0.f, v2t = 0.f;
    if (in) {
      v1  = 0.75f * d + 0.25f * (Ta[i][j] + d) / rows[n];   // M1[n][m]
      v2  = 0.75f * d + 0.25f * (Tb[j][i] + d) / cols[n];   // M2[n][m]
      v1t = 0.75f * d + 0.25f * (Tb[j][i] + d) / rows[m];   // M1[m][n]
      v2t = 0.75f * d + 0.25f * (Ta[i][j] + d) / cols[m];   // M2[m][n]
    }
    size_t o = (size_t)n * NP + m;
    unsigned short h;
    h = f2bf(v1);  M1h[o]  = h; M1l[o]  = f2bf(v1  - bf2f(h));
    h = f2bf(v2);  M2h[o]  = h; M2l[o]  = f2bf(v2  - bf2f(h));
    h = f2bf(v1t); M1Th[o] = h; M1Tl[o] = f2bf(v1t - bf2f(h));
    h = f2bf(v2t); M2Th[o] = h; M2Tl[o] = f2bf(v2t - bf2f(h));
  }
}

// channel-space word matrices Cm[7][32][2] and the constant channel vector
__global__ void k_prep(const float* __restrict__ wS, const float* __restrict__ bS,
                       const float* __restrict__ G1, const float* __restrict__ bg1,
                       const float* __restrict__ G2, const float* __restrict__ bg2,
                       float* __restrict__ Cm, float* __restrict__ cvec) {
  __shared__ float A1[64], A2[64], u1[32], v2[32];
  int t = threadIdx.x;          // 64 threads
  int c = t >> 1, ci = t & 1;
  Cm[t] = wS[c * 2 + ci];       // w0 = S
  float a1 = 0.f, a2 = 0.f;
  for (int j = 0; j < 32; ++j) {
    a1 += G1[c * 32 + j] * wS[j * 2 + ci];
    a2 += G2[c * 32 + j] * wS[j * 2 + ci];
  }
  A1[t] = a1; A2[t] = a2;
  Cm[64 + t] = a1;              // w1 = G1 S
  Cm[128 + t] = a2;             // w2 = G2 S
  __syncthreads();
  float b11 = 0, b12 = 0, b21 = 0, b22 = 0;
  for (int j = 0; j < 32; ++j) {
    b11 += G1[c * 32 + j] * A1[j * 2 + ci];
    b12 += G1[c * 32 + j] * A2[j * 2 + ci];
    b21 += G2[c * 32 + j] * A1[j * 2 + ci];
    b22 += G2[c * 32 + j] * A2[j * 2 + ci];
  }
  Cm[192 + t] = 0.25f * b11;    // pairs P1Y1 (Z11)
  Cm[256 + t] = 0.25f * b12;    // pairs P1Y2 (Z12)
  Cm[320 + t] = 0.25f * b21;    // pairs P2Y1 (Z21)
  Cm[384 + t] = 0.25f * b22;    // pairs P2Y2 (Z22)
  if (t < 32) {
    float uu = 0.f, vv = 0.f;
    for (int j = 0; j < 32; ++j) {
      float F = G1[t * 32 + j] + G2[t * 32 + j];
      uu += F * bS[j];
      vv += F * (bg1[j] + bg2[j]);
    }
    u1[t] = uu; v2[t] = vv;
  }
  __syncthreads();
  if (t < 32) {
    float u2v = 0.f;
    for (int j = 0; j < 32; ++j)
      u2v += (G1[t * 32 + j] + G2[t * 32 + j]) * u1[j];
    cvec[t] = bS[t] + u1[t] + 0.25f * u2v + (bg1[t] + bg2[t]) + 0.25f * v2[t];
  }
}

// ---- split-bf16 MFMA GEMM, NT-form ----
// C[M,N] = A@B. A given row-major [M][K] as (ah,al); B given TRANSPOSED
// row-major [N][K] as (bh,bl). 3-term: ah*bh + ah*bl + al*bh.
// BM=128, BK=32, 256 threads = 4 waves (2x2), per-wave 64 x BN_/2 tile.
// M,N multiples of tile; K multiple of 32 (all dims pre-padded -> no guards).
struct MG {
  const unsigned short *ah, *al, *bh, *bl;
  unsigned short *ch, *cl;      // split output (OUTF32=0)
  float *cf;                    // f32 output  (OUTF32=1)
};

template <int BN_, int OUTF32>
__global__ __launch_bounds__(256) void mgemm(MG g0, MG g1, int lda, int ldb,
                                             int ldc, int K) {
  MG g = (blockIdx.z == 0) ? g0 : g1;
  __shared__ __align__(16) unsigned short sAh[128 * 32];
  __shared__ __align__(16) unsigned short sAl[128 * 32];
  __shared__ __align__(16) unsigned short sBh[BN_ * 32];
  __shared__ __align__(16) unsigned short sBl[BN_ * 32];
  const int tid = threadIdx.x;
  const int wid = tid >> 6, lane = tid & 63;
  const int row0 = blockIdx.y * 128, col0 = blockIdx.x * BN_;
  const int FN = BN_ / 32;            // frags per wave in N (128->4, 64->2)
  const int wr = (wid >> 1) * 64;
  const int wc = (wid & 1) * (BN_ / 2);
  const int lr = lane & 15;
  const int lk = (lane >> 4) * 8;
  const int r16 = lane >> 2;          // staging: row within 16-row chunk
  const int k16 = (lane & 3) * 8;     // staging: element offset within row
  const int BCH = BN_ / 16;           // B chunks per matrix
  const int CPW = (16 + 2 * BCH) / 4; // chunks per wave (8 or 6)

  f32x4 acc[4][FN];
  #pragma unroll
  for (int m = 0; m < 4; ++m)
    #pragma unroll
    for (int n = 0; n < FN; ++n) acc[m][n] = {0.f, 0.f, 0.f, 0.f};

  for (int k0 = 0; k0 < K; k0 += 32) {
    #pragma unroll
    for (int c = 0; c < CPW; ++c) {
      int gch = wid * CPW + c;
      const unsigned short* src;
      unsigned short* dst;
      if (gch < 16) {
        int q = gch & 7;
        src = (gch < 8 ? g.ah : g.al) + (size_t)(row0 + q * 16 + r16) * lda + k0 + k16;
        dst = (gch < 8 ? sAh : sAl) + q * 512;
      } else {
        int gb = gch - 16;
        int q = (gb < BCH) ? gb : gb - BCH;
        src = (gb < BCH ? g.bh : g.bl) + (size_t)(col0 + q * 16 + r16) * ldb + k0 + k16;
        dst = (gb < BCH ? sBh : sBl) + q * 512;
      }
      gld16(src, dst);
    }
    __syncthreads();    // compiler drains vmcnt before barrier -> LDS valid
    short8 ahf[4], alf[4], bhf[FN], blf[FN];
    #pragma unroll
    for (int m = 0; m < 4; ++m) {
      ahf[m] = *(const short8*)&sAh[(wr + m * 16 + lr) * 32 + lk];
      alf[m] = *(const short8*)&sAl[(wr + m * 16 + lr) * 32 + lk];
    }
    #pragma unroll
    for (int n = 0; n < FN; ++n) {
      bhf[n] = *(const short8*)&sBh[(wc + n * 16 + lr) * 32 + lk];
      blf[n] = *(const short8*)&sBl[(wc + n * 16 + lr) * 32 + lk];
    }
    #pragma unroll
    for (int m = 0; m < 4; ++m)
      #pragma unroll
      for (int n = 0; n < FN; ++n) {
        acc[m][n] = __builtin_amdgcn_mfma_f32_16x16x32_bf16(ahf[m], bhf[n], acc[m][n], 0, 0, 0);
        acc[m][n] = __builtin_amdgcn_mfma_f32_16x16x32_bf16(ahf[m], blf[n], acc[m][n], 0, 0, 0);
        acc[m][n] = __builtin_amdgcn_mfma_f32_16x16x32_bf16(alf[m], bhf[n], acc[m][n], 0, 0, 0);
      }
    __syncthreads();
  }
  // epilogue: C layout col=lane&15, row=(lane>>4)*4+r  [m89-verified]
  #pragma unroll
  for (int m = 0; m < 4; ++m)
    #pragma unroll
    for (int n = 0; n < FN; ++n)
      #pragma unroll
      for (int r = 0; r < 4; ++r) {
        int row = row0 + wr + m * 16 + (lane >> 4) * 4 + r;
        int col = col0 + wc + n * 16 + lr;
        float v = acc[m][n][r];
        if (OUTF32) {
          g.cf[(size_t)row * ldc + col] = v;
        } else {
          unsigned short h = f2bf(v);
          g.ch[(size_t)row * ldc + col] = h;
          g.cl[(size_t)row * ldc + col] = f2bf(v - bf2f(h));
        }
      }
}

// 2048x2048 bf16 transpose, z selects matrix (4 matrices)
__global__ void k_transpose(const unsigned short* __restrict__ S,
                            unsigned short* __restrict__ D) {
  const unsigned short* src = S + (size_t)blockIdx.z * 4194304;
  unsigned short* dst = D + (size_t)blockIdx.z * 4194304;
  __shared__ unsigned short t[64][72];
  int bx = blockIdx.x * 64, by = blockIdx.y * 64;
  int tid = threadIdx.x;
  int i0 = tid >> 4, j0 = (tid & 15) * 4;
  #pragma unroll
  for (int p = 0; p < 4; ++p) {
    int i = i0 + p * 16;
    ushort4 v = *(const ushort4*)&src[(size_t)(by + i) * NP + bx + j0];
    t[j0 + 0][i] = v.x; t[j0 + 1][i] = v.y; t[j0 + 2][i] = v.z; t[j0 + 3][i] = v.w;
  }
  __syncthreads();
  #pragma unroll
  for (int p = 0; p < 4; ++p) {
    int i = i0 + p * 16;
    ushort4 v;
    v.x = t[i][j0]; v.y = t[i][j0 + 1]; v.z = t[i][j0 + 2]; v.w = t[i][j0 + 3];
    *(ushort4*)&dst[(size_t)(bx + i) * NP + by + j0] = v;
  }
}

// X[n][p] fp32 (2000x384): X[n, (b*12+l)*2+ci] = x[b,l,n,ci]
__global__ void k_buildX(const float* __restrict__ xin, float* __restrict__ X) {
  int idx = blockIdx.x * 256 + threadIdx.x;
  if (idx >= NN * SW) return;
  int n = idx / SW, p = idx % SW;
  int bl = p >> 1, ci = p & 1;
  X[idx] = xin[((size_t)bl * NN + n) * 2 + ci];
}

// XT[q][n] split bf16 [384][2048], zero-padded
__global__ void k_buildXT(const float* __restrict__ xin,
                          unsigned short* __restrict__ XTh,
                          unsigned short* __restrict__ XTl) {
  int idx = blockIdx.x * 256 + threadIdx.x;
  if (idx >= SW * NP) return;
  int q = idx >> 11, n = idx & (NP - 1);
  float v = 0.f;
  if (n < NN) {
    int bl = q >> 1, ci = q & 1;
    v = xin[((size_t)bl * NN + n) * 2 + ci];
  }
  unsigned short h = f2bf(v);
  XTh[idx] = h; XTl[idx] = f2bf(v - bf2f(h));
}

// YT[q][n] split bf16 [768][2048]: YT[q][n] = Yf[n + (q>=384)*2048][q%384]
__global__ void k_reshapeYT(const float* __restrict__ Yf,
                            unsigned short* __restrict__ YTh,
                            unsigned short* __restrict__ YTl) {
  __shared__ float t[64][65];
  int q0 = blockIdx.x * 64;              // 12 blocks
  int n0 = blockIdx.y * 64;              // 32 blocks
  int half = (q0 >= 384) ? 2048 : 0;
  int qs = (q0 >= 384) ? q0 - 384 : q0;
  int tid = threadIdx.x;
  int i0 = tid >> 4, j0 = (tid & 15) * 4;
  #pragma unroll
  for (int p = 0; p < 4; ++p) {
    int i = i0 + p * 16;
    float4 v = *(const float4*)&Yf[(size_t)(half + n0 + i) * SW + qs + j0];
    t[j0 + 0][i] = v.x; t[j0 + 1][i] = v.y; t[j0 + 2][i] = v.z; t[j0 + 3][i] = v.w;
  }
  __syncthreads();
  #pragma unroll
  for (int p = 0; p < 4; ++p) {
    int i = i0 + p * 16;          // q offset
    #pragma unroll
    for (int j = 0; j < 4; ++j) {
      float v = t[i][j0 + j];
      size_t o = (size_t)(q0 + i) * NP + n0 + j0 + j;
      unsigned short h = f2bf(v);
      YTh[o] = h; YTl[o] = f2bf(v - bf2f(h));
    }
  }
}

// H[n, b*384+l*32+c] = cvec[c] + sum_w Cm[w][c][:] . slab_w
__global__ void k_combine(const float* __restrict__ X, const float* __restrict__ Yf,
                          const float* __restrict__ Zf, const float* __restrict__ Cm,
                          const float* __restrict__ cvec, float* __restrict__ H) {
  int idx = blockIdx.x * 256 + threadIdx.x;
  if (idx >= NN * KW) return;
  int n = idx / KW, j = idx % KW;
  int b = j / 384, r = j % 384;
  int l = r >> 5, c = r & 31;
  int p2 = (b * NL + l) * 2;
  int c2 = c * 2;
  size_t pX  = (size_t)n * SW + p2;
  size_t pY2 = (size_t)(2048 + n) * SW + p2;
  size_t pZ1 = (size_t)n * 768 + p2;
  size_t pZ2 = (size_t)(2048 + n) * 768 + p2;
  float acc = cvec[c];
  acc += Cm[c2] * X[pX] + Cm[c2 + 1] * X[pX + 1];
  acc += Cm[64 + c2] * Yf[pX] + Cm[64 + c2 + 1] * Yf[pX + 1];
  acc += Cm[128 + c2] * Yf[pY2] + Cm[128 + c2 + 1] * Yf[pY2 + 1];
  acc += Cm[192 + c2] * Zf[pZ1] + Cm[192 + c2 + 1] * Zf[pZ1 + 1];
  acc += Cm[256 + c2] * Zf[pZ1 + 384] + Cm[256 + c2 + 1] * Zf[pZ1 + 385];
  acc += Cm[320 + c2] * Zf[pZ2] + Cm[320 + c2 + 1] * Zf[pZ2 + 1];
  acc += Cm[384 + c2] * Zf[pZ2 + 384] + Cm[384 + c2 + 1] * Zf[pZ2 + 385];
  H[idx] = acc;
}

__global__ void k_lnreduce(const float* __restrict__ H, float* __restrict__ ln) {
  __shared__ float sb[4];
  int b = blockIdx.x & 15, chunk = blockIdx.x >> 4;
  int n0 = chunk * 125;
  float s = 0.f, ss = 0.f;
  for (int t = threadIdx.x; t < 125 * 96; t += 256) {
    int n = n0 + t / 96, q = t % 96;
    float4 v = *(const float4*)(H + (size_t)n * KW + b * 384 + q * 4);
    s += v.x + v.y + v.z + v.w;
    ss += v.x * v.x + v.y * v.y + v.z * v.z + v.w * v.w;
  }
  s = blockReduceSum(s, sb);
  __syncthreads();
  ss = blockReduceSum(ss, sb);
  if (threadIdx.x == 0) { atomicAdd(&ln[b], s); atomicAdd(&ln[16 + b], ss); }
}

// __launch_bounds__(256, 2): 2 waves/EU -> 256-VGPR budget. Without the
// min-waves hint the allocator capped at 52 VGPRs and spilled y0[64] to
// scratch (r7 counters: VGPR=52, dur 170us = 3x the 57us FMA floor).
__global__ __launch_bounds__(256, 2) void k_epilogue(
    const float* __restrict__ H, const float* __restrict__ ln,
    const float* __restrict__ w0, const float* __restrict__ b0,
    const float* __restrict__ w1, const float* __restrict__ b1,
    const float* __restrict__ w2, const float* __restrict__ b2,
    float* __restrict__ out) {
  int p = blockIdx.x * 256 + threadIdx.x;
  if (p >= NB * NL * NN) return;
  int b = p / (NL * NN);
  int r = p % (NL * NN);
  int l = r / NN;
  int n = r % NN;
  float mu = ln[b] * (1.0f / LNCNT);
  float var = ln[16 + b] * (1.0f / LNCNT) - mu * mu;
  float rs = rsqrtf(fmaxf(var, 0.f) + 1e-5f);
  float x[32];
  const float* hp = H + (size_t)n * KW + b * 384 + l * 32;
  #pragma unroll
  for (int q = 0; q < 8; ++q) {
    float4 v = *(const float4*)(hp + q * 4);
    x[q * 4 + 0] = (v.x - mu) * rs;
    x[q * 4 + 1] = (v.y - mu) * rs;
    x[q * 4 + 2] = (v.z - mu) * rs;
    x[q * 4 + 3] = (v.w - mu) * rs;
  }
  float y0[64];
  #pragma unroll
  for (int o = 0; o < 64; ++o) {
    float acc = b0[o];
    const float* wr = w0 + o * 32;
    #pragma unroll
    for (int i = 0; i < 32; ++i) acc += wr[i] * x[i];
    y0[o] = fmaxf(acc, 0.f);
  }
  float outv[12];
  #pragma unroll
  for (int o = 0; o < 12; ++o) outv[o] = b2[o];
  for (int jj = 0; jj < 128; ++jj) {
    float acc = b1[jj];
    const float* wr = w1 + jj * 64;
    #pragma unroll
    for (int i = 0; i < 64; ++i) acc += wr[i] * y0[i];
    acc = fmaxf(acc, 0.f);
    #pragma unroll
    for (int o = 0; o < 12; ++o) outv[o] += w2[o * 128 + jj] * acc;
  }
  float* op = out + ((size_t)(b * NL + l) * NN + n) * 12;
  #pragma unroll
  for (int o = 0; o < 12; ++o) op[o] = outv[o];
}

extern "C" void kernel_launch(void* const* d_in, const int* in_sizes, int n_in,
                              void* d_out, int out_size, void* d_ws, size_t ws_size,
                              hipStream_t stream) {
  (void)in_sizes; (void)n_in; (void)out_size; (void)ws_size;
  const float* x   = (const float*)d_in[0];
  const float* adj = (const float*)d_in[1];
  const float* wS  = (const float*)d_in[2];
  const float* bS  = (const float*)d_in[3];
  const float* G1  = (const float*)d_in[4];
  const float* bg1 = (const float*)d_in[5];
  const float* G2  = (const float*)d_in[6];
  const float* bg2 = (const float*)d_in[7];
  const float* we0 = (const float*)d_in[8];
  const float* be0 = (const float*)d_in[9];
  const float* we1 = (const float*)d_in[10];
  const float* be1 = (const float*)d_in[11];
  const float* we2 = (const float*)d_in[12];
  const float* be2 = (const float*)d_in[13];
  float* out = (float*)d_out;
  float* wsf = (float*)d_ws;

  float* rows = wsf + O_ROWS;
  float* cols = wsf + O_COLS;
  float* lnb  = wsf + O_LN;
  float* Cm   = wsf + O_CM;
  float* cvec = wsf + O_CV;

  unsigned short* M1h  = (unsigned short*)(wsf + R1);
  unsigned short* M1l  = (unsigned short*)(wsf + R1 + SZH);
  unsigned short* M2h  = (unsigned short*)(wsf + R1 + 2 * SZH);
  unsigned short* M2l  = (unsigned short*)(wsf + R1 + 3 * SZH);
  unsigned short* M1Th = (unsigned short*)(wsf + R2);
  unsigned short* M1Tl = (unsigned short*)(wsf + R2 + SZH);
  unsigned short* M2Th = (unsigned short*)(wsf + R2 + 2 * SZH);
  unsigned short* M2Tl = (unsigned short*)(wsf + R2 + 3 * SZH);
  unsigned short* T1h  = (unsigned short*)(wsf + R3);
  unsigned short* T1l  = (unsigned short*)(wsf + R3 + SZH);
  unsigned short* T2h  = (unsigned short*)(wsf + R3 + 2 * SZH);
  unsigned short* T2l  = (unsigned short*)(wsf + R3 + 3 * SZH);
  // T^T overlays R2 (M^T dead after GEMM1)
  unsigned short* T1Th = M1Th;
  unsigned short* T1Tl = M1Tl;
  unsigned short* T2Th = M2Th;
  unsigned short* T2Tl = M2Tl;
  // P overlays R1 (M dead after GEMM1): stacked [P1;P2] 4096x2048
  unsigned short* Phi  = (unsigned short*)(wsf + R1);
  unsigned short* Plo  = (unsigned short*)(wsf + R1 + 2 * SZH);
  // slabs overlay R3 (T dead after GEMM2)
  float* X   = wsf + O_X;
  unsigned short* XTh = (unsigned short*)(wsf + O_XTH);
  unsigned short* XTl = (unsigned short*)(wsf + O_XTL);
  float* Yf  = wsf + O_YF;
  unsigned short* YTh = (unsigned short*)(wsf + O_YTH);
  unsigned short* YTl = (unsigned short*)(wsf + O_YTL);
  float* Zf  = wsf + O_ZF;
  float* H   = wsf + O_H;   // overlays R1/R2 (P, TT dead by combine)

  hipMemsetAsync(lnb, 0, 32 * sizeof(float), stream);
  k_rowsum<<<NN, 256, 0, stream>>>(adj, rows);
  k_colsum<<<32, 256, 0, stream>>>(adj, cols);
  k_buildM8<<<dim3(32, 32), 256, 0, stream>>>(adj, rows, cols,
      M1h, M1l, M2h, M2l, M1Th, M1Tl, M2Th, M2Tl);
  k_prep<<<1, 64, 0, stream>>>(wS, bS, G1, bg1, G2, bg2, Cm, cvec);

  // GEMM1: T1 = M1@M1, T2 = M2@M2  (split out)
  {
    MG a0 = {M1h, M1l, M1Th, M1Tl, T1h, T1l, nullptr};
    MG a1 = {M2h, M2l, M2Th, M2Tl, T2h, T2l, nullptr};
    mgemm<128, 0><<<dim3(16, 16, 2), 256, 0, stream>>>(a0, a1, NP, NP, NP, NP);
  }
  // T^T (4 matrices)
  k_transpose<<<dim3(32, 32, 4), 256, 0, stream>>>(T1h, T1Th);
  // GEMM2: P1 = T1@T1, P2 = T2@T2 -> stacked [P1;P2]
  {
    MG b0 = {T1h, T1l, T1Th, T1Tl, Phi, Plo, nullptr};
    MG b1 = {T2h, T2l, T2Th, T2Tl, Phi + (size_t)NP * NP, Plo + (size_t)NP * NP, nullptr};
    mgemm<128, 0><<<dim3(16, 16, 2), 256, 0, stream>>>(b0, b1, NP, NP, NP, NP);
  }
  // slabs
  k_buildX<<<(NN * SW + 255) / 256, 256, 0, stream>>>(x, X);
  k_buildXT<<<(SW * NP + 255) / 256, 256, 0, stream>>>(x, XTh, XTl);
  // GEMM3: Yf = [P1;P2] @ X   (4096 x 384, f32 out)
  {
    MG c0 = {Phi, Plo, XTh, XTl, nullptr, nullptr, Yf};
    mgemm<64, 1><<<dim3(6, 32, 1), 256, 0, stream>>>(c0, c0, NP, NP, SW, NP);
  }
  k_reshapeYT<<<dim3(12, 32), 256, 0, stream>>>(Yf, YTh, YTl);
  // GEMM4: Zf = [P1;P2] @ [Y1|Y2]  (4096 x 768, f32 out)
  {
    MG e0 = {Phi, Plo, YTh, YTl, nullptr, nullptr, Zf};
    mgemm<64, 1><<<dim3(12, 32, 1), 256, 0, stream>>>(e0, e0, NP, NP, 768, NP);
  }

  k_combine<<<(NN * KW + 255) / 256, 256, 0, stream>>>(X, Yf, Zf, Cm, cvec, H);
  k_lnreduce<<<256, 256, 0, stream>>>(H, lnb);
  k_epilogue<<<(NB * NL * NN + 255) / 256, 256, 0, stream>>>(
      H, lnb, we0, be0, we1, be1, we2, be2, out);
}

// Round 9
// 859.169 us; speedup vs baseline: 2.0961x; 1.0040x over previous
//
#include <hip/hip_runtime.h>
#include <math.h>

// ---- problem constants ----
#define NN 2000     // nodes
#define NP 2048     // padded nodes
#define NB 16
#define NL 12
#define KW 6144     // NB*NL*32
#define SW 384      // NB*NL*2
#define LNCNT 768000.0f

// ---- workspace float offsets ----
#define O_ROWS ((size_t)0)
#define O_COLS ((size_t)2048)
#define O_LN   ((size_t)4096)
#define O_CM   ((size_t)4224)
#define O_CV   ((size_t)4672)
#define SZH ((size_t)2097152)
#define R1  ((size_t)8192)
#define R2  (R1 + 4*SZH)
#define R3  (R2 + 4*SZH)
#define O_X   (R3 + 0)
#define O_XTH (R3 + 768000)
#define O_XTL (O_XTH + 393216)
#define O_YF  (O_XTL + 393216)
#define O_YTH (O_YF + 1572864)
#define O_YTL (O_YTH + 786432)
#define O_ZF  (O_YTL + 786432)
#define O_H   R1

typedef __attribute__((ext_vector_type(8))) short short8;
typedef __attribute__((ext_vector_type(4))) float f32x4;

__device__ __forceinline__ unsigned short f2bf(float f) {
  union { float f; unsigned u; } x; x.f = f;
  unsigned r = x.u + 0x7fff + ((x.u >> 16) & 1);   // RNE
  return (unsigned short)(r >> 16);
}
__device__ __forceinline__ float bf2f(unsigned short b) {
  union { unsigned u; float f; } x; x.u = ((unsigned)b) << 16;
  return x.f;
}
__device__ __forceinline__ void gld16(const void* g, void* l) {
  __builtin_amdgcn_global_load_lds(
      (const __attribute__((address_space(1))) unsigned int*)g,
      (__attribute__((address_space(3))) unsigned int*)l, 16, 0, 0);
}

__device__ __forceinline__ float blockReduceSum(float v, float* sbuf) {
  #pragma unroll
  for (int off = 32; off > 0; off >>= 1) v += __shfl_down(v, off, 64);
  int wid = threadIdx.x >> 6, lane = threadIdx.x & 63;
  if (lane == 0) sbuf[wid] = v;
  __syncthreads();
  v = (threadIdx.x < 4) ? sbuf[threadIdx.x] : 0.f;
  if (threadIdx.x < 64) { v += __shfl_down(v, 2, 64); v += __shfl_down(v, 1, 64); }
  return v;
}

__global__ void k_rowsum(const float* __restrict__ adj, float* __restrict__ rows) {
  __shared__ float sb[4];
  int n = blockIdx.x;
  const float4* a4 = (const float4*)(adj + (size_t)n * NN);
  float s = 0.f;
  for (int t = threadIdx.x; t < NN / 4; t += 256) {
    float4 v = a4[t];
    s += v.x + v.y + v.z + v.w;
  }
  s = blockReduceSum(s, sb);
  if (threadIdx.x == 0) rows[n] = s + 1.0f;
}

__global__ void k_colsum(const float* __restrict__ adj, float* __restrict__ cols) {
  __shared__ float sb[4][64];
  int col = blockIdx.x * 64 + (threadIdx.x & 63);
  int rg = threadIdx.x >> 6;
  float s = 0.f;
  if (col < NN)
    for (int m = rg; m < NN; m += 4) s += adj[(size_t)m * NN + col];
  sb[rg][threadIdx.x & 63] = s;
  __syncthreads();
  if (rg == 0 && col < NN)
    cols[col] = sb[0][threadIdx.x] + sb[1][threadIdx.x] + sb[2][threadIdx.x] + sb[3][threadIdx.x] + 1.0f;
}

// Build split-bf16 M1, M2 AND their transposes, zero-padded to 2048x2048.
__global__ void k_buildM8(const float* __restrict__ adj, const float* __restrict__ rows,
                          const float* __restrict__ cols,
                          unsigned short* __restrict__ M1h, unsigned short* __restrict__ M1l,
                          unsigned short* __restrict__ M2h, unsigned short* __restrict__ M2l,
                          unsigned short* __restrict__ M1Th, unsigned short* __restrict__ M1Tl,
                          unsigned short* __restrict__ M2Th, unsigned short* __restrict__ M2Tl) {
  __shared__ float Ta[64][65];
  __shared__ float Tb[64][65];
  int r0 = blockIdx.y * 64, c0 = blockIdx.x * 64;
  for (int e = threadIdx.x; e < 4096; e += 256) {
    int i = e >> 6, j = e & 63;
    int rr = r0 + i, cc = c0 + j;
    Ta[i][j] = (rr < NN && cc < NN) ? adj[(size_t)rr * NN + cc] : 0.f;
    int rr2 = c0 + i, cc2 = r0 + j;
    Tb[i][j] = (rr2 < NN && cc2 < NN) ? adj[(size_t)rr2 * NN + cc2] : 0.f;
  }
  __syncthreads();
  for (int e = threadIdx.x; e < 4096; e += 256) {
    int i = e >> 6, j = e & 63;
    int n = r0 + i, m = c0 + j;
    bool in = (n < NN && m < NN);
    float d = (n == m) ? 1.f : 0.f;
    float v1 = 0.f, v2 = 0.f, v1t = 0.f, v2t = 0.f;
    if (in) {
      v1  = 0.75f * d + 0.25f * (Ta[i][j] + d) / rows[n];
      v2  = 0.75f * d + 0.25f * (Tb[j][i] + d) / cols[n];
      v1t = 0.75f * d + 0.25f * (Tb[j][i] + d) / rows[m];
      v2t = 0.75f * d + 0.25f * (Ta[i][j] + d) / cols[m];
    }
    size_t o = (size_t)n * NP + m;
    unsigned short h;
    h = f2bf(v1);  M1h[o]  = h; M1l[o]  = f2bf(v1  - bf2f(h));
    h = f2bf(v2);  M2h[o]  = h; M2l[o]  = f2bf(v2  - bf2f(h));
    h = f2bf(v1t); M1Th[o] = h; M1Tl[o] = f2bf(v1t - bf2f(h));
    h = f2bf(v2t); M2Th[o] = h; M2Tl[o] = f2bf(v2t - bf2f(h));
  }
}

// channel-space word matrices Cm[7][32][2] and the constant channel vector
__global__ void k_prep(const float* __restrict__ wS, const float* __restrict__ bS,
                       const float* __restrict__ G1, const float* __restrict__ bg1,
                       const float* __restrict__ G2, const float* __restrict__ bg2,
                       float* __restrict__ Cm, float* __restrict__ cvec) {
  __shared__ float A1[64], A2[64], u1[32], v2[32];
  int t = threadIdx.x;          // 64 threads
  int c = t >> 1, ci = t & 1;
  Cm[t] = wS[c * 2 + ci];
  float a1 = 0.f, a2 = 0.f;
  for (int j = 0; j < 32; ++j) {
    a1 += G1[c * 32 + j] * wS[j * 2 + ci];
    a2 += G2[c * 32 + j] * wS[j * 2 + ci];
  }
  A1[t] = a1; A2[t] = a2;
  Cm[64 + t] = a1;
  Cm[128 + t] = a2;
  __syncthreads();
  float b11 = 0, b12 = 0, b21 = 0, b22 = 0;
  for (int j = 0; j < 32; ++j) {
    b11 += G1[c * 32 + j] * A1[j * 2 + ci];
    b12 += G1[c * 32 + j] * A2[j * 2 + ci];
    b21 += G2[c * 32 + j] * A1[j * 2 + ci];
    b22 += G2[c * 32 + j] * A2[j * 2 + ci];
  }
  Cm[192 + t] = 0.25f * b11;
  Cm[256 + t] = 0.25f * b12;
  Cm[320 + t] = 0.25f * b21;
  Cm[384 + t] = 0.25f * b22;
  if (t < 32) {
    float uu = 0.f, vv = 0.f;
    for (int j = 0; j < 32; ++j) {
      float F = G1[t * 32 + j] + G2[t * 32 + j];
      uu += F * bS[j];
      vv += F * (bg1[j] + bg2[j]);
    }
    u1[t] = uu; v2[t] = vv;
  }
  __syncthreads();
  if (t < 32) {
    float u2v = 0.f;
    for (int j = 0; j < 32; ++j)
      u2v += (G1[t * 32 + j] + G2[t * 32 + j]) * u1[j];
    cvec[t] = bS[t] + u1[t] + 0.25f * u2v + (bg1[t] + bg2[t]) + 0.25f * v2[t];
  }
}

// ---- split-bf16 MFMA GEMM, NT-form ----
struct MG {
  const unsigned short *ah, *al, *bh, *bl;
  unsigned short *ch, *cl;      // split output (OUTF32=0)
  float *cf;                    // f32 output  (OUTF32=1)
};

template <int BN_, int OUTF32>
__global__ __launch_bounds__(256) void mgemm(MG g0, MG g1, int lda, int ldb,
                                             int ldc, int K) {
  MG g = (blockIdx.z == 0) ? g0 : g1;
  __shared__ __align__(16) unsigned short sAh[128 * 32];
  __shared__ __align__(16) unsigned short sAl[128 * 32];
  __shared__ __align__(16) unsigned short sBh[BN_ * 32];
  __shared__ __align__(16) unsigned short sBl[BN_ * 32];
  const int tid = threadIdx.x;
  const int wid = tid >> 6, lane = tid & 63;
  const int row0 = blockIdx.y * 128, col0 = blockIdx.x * BN_;
  const int FN = BN_ / 32;
  const int wr = (wid >> 1) * 64;
  const int wc = (wid & 1) * (BN_ / 2);
  const int lr = lane & 15;
  const int lk = (lane >> 4) * 8;
  const int r16 = lane >> 2;
  const int k16 = (lane & 3) * 8;
  const int BCH = BN_ / 16;
  const int CPW = (16 + 2 * BCH) / 4;

  f32x4 acc[4][FN];
  #pragma unroll
  for (int m = 0; m < 4; ++m)
    #pragma unroll
    for (int n = 0; n < FN; ++n) acc[m][n] = {0.f, 0.f, 0.f, 0.f};

  for (int k0 = 0; k0 < K; k0 += 32) {
    #pragma unroll
    for (int c = 0; c < CPW; ++c) {
      int gch = wid * CPW + c;
      const unsigned short* src;
      unsigned short* dst;
      if (gch < 16) {
        int q = gch & 7;
        src = (gch < 8 ? g.ah : g.al) + (size_t)(row0 + q * 16 + r16) * lda + k0 + k16;
        dst = (gch < 8 ? sAh : sAl) + q * 512;
      } else {
        int gb = gch - 16;
        int q = (gb < BCH) ? gb : gb - BCH;
        src = (gb < BCH ? g.bh : g.bl) + (size_t)(col0 + q * 16 + r16) * ldb + k0 + k16;
        dst = (gb < BCH ? sBh : sBl) + q * 512;
      }
      gld16(src, dst);
    }
    __syncthreads();
    short8 ahf[4], alf[4], bhf[FN], blf[FN];
    #pragma unroll
    for (int m = 0; m < 4; ++m) {
      ahf[m] = *(const short8*)&sAh[(wr + m * 16 + lr) * 32 + lk];
      alf[m] = *(const short8*)&sAl[(wr + m * 16 + lr) * 32 + lk];
    }
    #pragma unroll
    for (int n = 0; n < FN; ++n) {
      bhf[n] = *(const short8*)&sBh[(wc + n * 16 + lr) * 32 + lk];
      blf[n] = *(const short8*)&sBl[(wc + n * 16 + lr) * 32 + lk];
    }
    #pragma unroll
    for (int m = 0; m < 4; ++m)
      #pragma unroll
      for (int n = 0; n < FN; ++n) {
        acc[m][n] = __builtin_amdgcn_mfma_f32_16x16x32_bf16(ahf[m], bhf[n], acc[m][n], 0, 0, 0);
        acc[m][n] = __builtin_amdgcn_mfma_f32_16x16x32_bf16(ahf[m], blf[n], acc[m][n], 0, 0, 0);
        acc[m][n] = __builtin_amdgcn_mfma_f32_16x16x32_bf16(alf[m], bhf[n], acc[m][n], 0, 0, 0);
      }
    __syncthreads();
  }
  #pragma unroll
  for (int m = 0; m < 4; ++m)
    #pragma unroll
    for (int n = 0; n < FN; ++n)
      #pragma unroll
      for (int r = 0; r < 4; ++r) {
        int row = row0 + wr + m * 16 + (lane >> 4) * 4 + r;
        int col = col0 + wc + n * 16 + lr;
        float v = acc[m][n][r];
        if (OUTF32) {
          g.cf[(size_t)row * ldc + col] = v;
        } else {
          unsigned short h = f2bf(v);
          g.ch[(size_t)row * ldc + col] = h;
          g.cl[(size_t)row * ldc + col] = f2bf(v - bf2f(h));
        }
      }
}

// 2048x2048 bf16 transpose, z selects matrix (4 matrices)
__global__ void k_transpose(const unsigned short* __restrict__ S,
                            unsigned short* __restrict__ D) {
  const unsigned short* src = S + (size_t)blockIdx.z * 4194304;
  unsigned short* dst = D + (size_t)blockIdx.z * 4194304;
  __shared__ unsigned short t[64][72];
  int bx = blockIdx.x * 64, by = blockIdx.y * 64;
  int tid = threadIdx.x;
  int i0 = tid >> 4, j0 = (tid & 15) * 4;
  #pragma unroll
  for (int p = 0; p < 4; ++p) {
    int i = i0 + p * 16;
    ushort4 v = *(const ushort4*)&src[(size_t)(by + i) * NP + bx + j0];
    t[j0 + 0][i] = v.x; t[j0 + 1][i] = v.y; t[j0 + 2][i] = v.z; t[j0 + 3][i] = v.w;
  }
  __syncthreads();
  #pragma unroll
  for (int p = 0; p < 4; ++p) {
    int i = i0 + p * 16;
    ushort4 v;
    v.x = t[i][j0]; v.y = t[i][j0 + 1]; v.z = t[i][j0 + 2]; v.w = t[i][j0 + 3];
    *(ushort4*)&dst[(size_t)(bx + i) * NP + by + j0] = v;
  }
}

// X[n][p] fp32 (2000x384)
__global__ void k_buildX(const float* __restrict__ xin, float* __restrict__ X) {
  int idx = blockIdx.x * 256 + threadIdx.x;
  if (idx >= NN * SW) return;
  int n = idx / SW, p = idx % SW;
  int bl = p >> 1, ci = p & 1;
  X[idx] = xin[((size_t)bl * NN + n) * 2 + ci];
}

// XT[q][n] split bf16 [384][2048], zero-padded
__global__ void k_buildXT(const float* __restrict__ xin,
                          unsigned short* __restrict__ XTh,
                          unsigned short* __restrict__ XTl) {
  int idx = blockIdx.x * 256 + threadIdx.x;
  if (idx >= SW * NP) return;
  int q = idx >> 11, n = idx & (NP - 1);
  float v = 0.f;
  if (n < NN) {
    int bl = q >> 1, ci = q & 1;
    v = xin[((size_t)bl * NN + n) * 2 + ci];
  }
  unsigned short h = f2bf(v);
  XTh[idx] = h; XTl[idx] = f2bf(v - bf2f(h));
}

// YT[q][n] split bf16 [768][2048]
__global__ void k_reshapeYT(const float* __restrict__ Yf,
                            unsigned short* __restrict__ YTh,
                            unsigned short* __restrict__ YTl) {
  __shared__ float t[64][65];
  int q0 = blockIdx.x * 64;
  int n0 = blockIdx.y * 64;
  int half = (q0 >= 384) ? 2048 : 0;
  int qs = (q0 >= 384) ? q0 - 384 : q0;
  int tid = threadIdx.x;
  int i0 = tid >> 4, j0 = (tid & 15) * 4;
  #pragma unroll
  for (int p = 0; p < 4; ++p) {
    int i = i0 + p * 16;
    float4 v = *(const float4*)&Yf[(size_t)(half + n0 + i) * SW + qs + j0];
    t[j0 + 0][i] = v.x; t[j0 + 1][i] = v.y; t[j0 + 2][i] = v.z; t[j0 + 3][i] = v.w;
  }
  __syncthreads();
  #pragma unroll
  for (int p = 0; p < 4; ++p) {
    int i = i0 + p * 16;
    #pragma unroll
    for (int j = 0; j < 4; ++j) {
      float v = t[i][j0 + j];
      size_t o = (size_t)(q0 + i) * NP + n0 + j0 + j;
      unsigned short h = f2bf(v);
      YTh[o] = h; YTl[o] = f2bf(v - bf2f(h));
    }
  }
}

// H[n, b*384+l*32+c] = cvec[c] + sum_w Cm[w][c][:] . slab_w
__global__ void k_combine(const float* __restrict__ X, const float* __restrict__ Yf,
                          const float* __restrict__ Zf, const float* __restrict__ Cm,
                          const float* __restrict__ cvec, float* __restrict__ H) {
  int idx = blockIdx.x * 256 + threadIdx.x;
  if (idx >= NN * KW) return;
  int n = idx / KW, j = idx % KW;
  int b = j / 384, r = j % 384;
  int l = r >> 5, c = r & 31;
  int p2 = (b * NL + l) * 2;
  int c2 = c * 2;
  size_t pX  = (size_t)n * SW + p2;
  size_t pY2 = (size_t)(2048 + n) * SW + p2;
  size_t pZ1 = (size_t)n * 768 + p2;
  size_t pZ2 = (size_t)(2048 + n) * 768 + p2;
  float acc = cvec[c];
  acc += Cm[c2] * X[pX] + Cm[c2 + 1] * X[pX + 1];
  acc += Cm[64 + c2] * Yf[pX] + Cm[64 + c2 + 1] * Yf[pX + 1];
  acc += Cm[128 + c2] * Yf[pY2] + Cm[128 + c2 + 1] * Yf[pY2 + 1];
  acc += Cm[192 + c2] * Zf[pZ1] + Cm[192 + c2 + 1] * Zf[pZ1 + 1];
  acc += Cm[256 + c2] * Zf[pZ1 + 384] + Cm[256 + c2 + 1] * Zf[pZ1 + 385];
  acc += Cm[320 + c2] * Zf[pZ2] + Cm[320 + c2 + 1] * Zf[pZ2 + 1];
  acc += Cm[384 + c2] * Zf[pZ2 + 384] + Cm[384 + c2 + 1] * Zf[pZ2 + 385];
  H[idx] = acc;
}

__global__ void k_lnreduce(const float* __restrict__ H, float* __restrict__ ln) {
  __shared__ float sb[4];
  int b = blockIdx.x & 15, chunk = blockIdx.x >> 4;
  int n0 = chunk * 125;
  float s = 0.f, ss = 0.f;
  for (int t = threadIdx.x; t < 125 * 96; t += 256) {
    int n = n0 + t / 96, q = t % 96;
    float4 v = *(const float4*)(H + (size_t)n * KW + b * 384 + q * 4);
    s += v.x + v.y + v.z + v.w;
    ss += v.x * v.x + v.y * v.y + v.z * v.z + v.w * v.w;
  }
  s = blockReduceSum(s, sb);
  __syncthreads();
  ss = blockReduceSum(ss, sb);
  if (threadIdx.x == 0) { atomicAdd(&ln[b], s); atomicAdd(&ln[16 + b], ss); }
}

// ---- MFMA epilogue ----
// r8 post-mortem: VALU epilogue stuck at 163us (2.9x FMA floor) because the
// allocator parks y0[64] in AGPRs (VGPR_Count=52 regardless of launch bounds;
// zero scratch traffic) -> every y0 use pays v_accvgpr_read. Fix: run the
// 3-layer MLP on the matrix pipe. Full 3-term split-bf16 (same arithmetic as
// mgemm) at every layer; LN+bias+relu fused; intermediates re-shaped via
// padded LDS (+8 bf16/row -> 2-way bank access, free per m136).
// Block: 256 thr = 4 waves x 16 rows. Grid (32 n-tiles, 192 (b,l)).
__global__ __launch_bounds__(256) void k_epilogue_mfma(
    const float* __restrict__ H, const float* __restrict__ ln,
    const float* __restrict__ w0, const float* __restrict__ b0,
    const float* __restrict__ w1, const float* __restrict__ b1,
    const float* __restrict__ w2, const float* __restrict__ b2,
    float* __restrict__ out) {
  __shared__ __align__(16) unsigned short sW0h[64 * 40], sW0l[64 * 40];
  __shared__ __align__(16) unsigned short sW1h[128 * 72], sW1l[128 * 72];
  __shared__ __align__(16) unsigned short sW2h[16 * 136], sW2l[16 * 136];
  __shared__ __align__(16) unsigned short sY0h[4 * 16 * 72], sY0l[4 * 16 * 72];
  __shared__ __align__(16) unsigned short sY1h[4 * 16 * 136], sY1l[4 * 16 * 136];
  __shared__ float b0s[64], b1s[128];
  const int tid = threadIdx.x;

  // ---- stage weights (split bf16, padded rows) ----
  {  // W0 [64][32] -> [64][40]
    int t0 = tid * 8, r = t0 >> 5, c = t0 & 31;
    float4 a = *(const float4*)(w0 + t0);
    float4 bq = *(const float4*)(w0 + t0 + 4);
    float v[8] = {a.x, a.y, a.z, a.w, bq.x, bq.y, bq.z, bq.w};
    short8 vh, vl;
    #pragma unroll
    for (int j = 0; j < 8; ++j) {
      unsigned short h = f2bf(v[j]);
      vh[j] = (short)h; vl[j] = (short)f2bf(v[j] - bf2f(h));
    }
    *(short8*)&sW0h[r * 40 + c] = vh;
    *(short8*)&sW0l[r * 40 + c] = vl;
  }
  #pragma unroll
  for (int q = 0; q < 4; ++q) {  // W1 [128][64] -> [128][72]
    int idx = tid * 32 + q * 8, r = idx >> 6, c = idx & 63;
    float4 a = *(const float4*)(w1 + idx);
    float4 bq = *(const float4*)(w1 + idx + 4);
    float v[8] = {a.x, a.y, a.z, a.w, bq.x, bq.y, bq.z, bq.w};
    short8 vh, vl;
    #pragma unroll
    for (int j = 0; j < 8; ++j) {
      unsigned short h = f2bf(v[j]);
      vh[j] = (short)h; vl[j] = (short)f2bf(v[j] - bf2f(h));
    }
    *(short8*)&sW1h[r * 72 + c] = vh;
    *(short8*)&sW1l[r * 72 + c] = vl;
  }
  {  // W2 [12][128] -> [16][136] zero-padded rows 12..15
    int idx = tid * 8, r = idx >> 7, c = idx & 127;
    float v[8] = {0, 0, 0, 0, 0, 0, 0, 0};
    if (r < 12) {
      float4 a = *(const float4*)(w2 + r * 128 + c);
      float4 bq = *(const float4*)(w2 + r * 128 + c + 4);
      v[0] = a.x; v[1] = a.y; v[2] = a.z; v[3] = a.w;
      v[4] = bq.x; v[5] = bq.y; v[6] = bq.z; v[7] = bq.w;
    }
    short8 vh, vl;
    #pragma unroll
    for (int j = 0; j < 8; ++j) {
      unsigned short h = f2bf(v[j]);
      vh[j] = (short)h; vl[j] = (short)f2bf(v[j] - bf2f(h));
    }
    *(short8*)&sW2h[r * 136 + c] = vh;
    *(short8*)&sW2l[r * 136 + c] = vl;
  }
  if (tid < 64) b0s[tid] = b0[tid];
  if (tid < 128) b1s[tid] = b1[tid];
  __syncthreads();

  const int wid = tid >> 6, lane = tid & 63;
  const int lr = lane & 15, hk = lane >> 4;  // hk 0..3
  const int lk = hk * 8;
  const int bl = blockIdx.y, bb = bl / 12, ll = bl % 12;
  const int ntile = blockIdx.x * 64 + wid * 16;

  const float mu = ln[bb] * (1.0f / LNCNT);
  const float var = ln[16 + bb] * (1.0f / LNCNT) - mu * mu;
  const float rs = rsqrtf(fmaxf(var, 0.f) + 1e-5f);

  // ---- A0 frag: LN-normalized x, split bf16 ----
  short8 ah = {0, 0, 0, 0, 0, 0, 0, 0}, al = ah;
  {
    int n_row = ntile + lr;
    if (n_row < NN) {
      const float* hp = H + (size_t)n_row * KW + bb * 384 + ll * 32 + lk;
      float4 v0 = *(const float4*)hp;
      float4 v1 = *(const float4*)(hp + 4);
      float xs[8] = {v0.x, v0.y, v0.z, v0.w, v1.x, v1.y, v1.z, v1.w};
      #pragma unroll
      for (int j = 0; j < 8; ++j) {
        float xv = (xs[j] - mu) * rs;
        unsigned short h = f2bf(xv);
        ah[j] = (short)h; al[j] = (short)f2bf(xv - bf2f(h));
      }
    }
  }

  // ---- E0: [16x32] @ W0^T -> y0 [16][64] ----
  const int y0b = wid * 16 * 72;
  {
    f32x4 acc0[4];
    #pragma unroll
    for (int nf = 0; nf < 4; ++nf) {
      short8 bh = *(const short8*)&sW0h[(nf * 16 + lr) * 40 + lk];
      short8 bo = *(const short8*)&sW0l[(nf * 16 + lr) * 40 + lk];
      f32x4 a = {0.f, 0.f, 0.f, 0.f};
      a = __builtin_amdgcn_mfma_f32_16x16x32_bf16(ah, bh, a, 0, 0, 0);
      a = __builtin_amdgcn_mfma_f32_16x16x32_bf16(ah, bo, a, 0, 0, 0);
      a = __builtin_amdgcn_mfma_f32_16x16x32_bf16(al, bh, a, 0, 0, 0);
      acc0[nf] = a;
    }
    #pragma unroll
    for (int nf = 0; nf < 4; ++nf)
      #pragma unroll
      for (int r = 0; r < 4; ++r) {
        int row = hk * 4 + r, col = nf * 16 + lr;
        float v = fmaxf(acc0[nf][r] + b0s[col], 0.f);
        unsigned short h = f2bf(v);
        sY0h[y0b + row * 72 + col] = h;
        sY0l[y0b + row * 72 + col] = f2bf(v - bf2f(h));
      }
  }
  __syncthreads();

  // ---- E1: [16x64] @ W1^T -> y1 [16][128] ----
  const int y1b = wid * 16 * 136;
  {
    short8 a1h[2], a1l[2];
    #pragma unroll
    for (int kc = 0; kc < 2; ++kc) {
      a1h[kc] = *(const short8*)&sY0h[y0b + lr * 72 + kc * 32 + lk];
      a1l[kc] = *(const short8*)&sY0l[y0b + lr * 72 + kc * 32 + lk];
    }
    f32x4 acc1[8];
    #pragma unroll
    for (int nf = 0; nf < 8; ++nf) {
      f32x4 a = {0.f, 0.f, 0.f, 0.f};
      #pragma unroll
      for (int kc = 0; kc < 2; ++kc) {
        short8 bh = *(const short8*)&sW1h[(nf * 16 + lr) * 72 + kc * 32 + lk];
        short8 bo = *(const short8*)&sW1l[(nf * 16 + lr) * 72 + kc * 32 + lk];
        a = __builtin_amdgcn_mfma_f32_16x16x32_bf16(a1h[kc], bh, a, 0, 0, 0);
        a = __builtin_amdgcn_mfma_f32_16x16x32_bf16(a1h[kc], bo, a, 0, 0, 0);
        a = __builtin_amdgcn_mfma_f32_16x16x32_bf16(a1l[kc], bh, a, 0, 0, 0);
      }
      acc1[nf] = a;
    }
    #pragma unroll
    for (int nf = 0; nf < 8; ++nf)
      #pragma unroll
      for (int r = 0; r < 4; ++r) {
        int row = hk * 4 + r, col = nf * 16 + lr;
        float v = fmaxf(acc1[nf][r] + b1s[col], 0.f);
        unsigned short h = f2bf(v);
        sY1h[y1b + row * 136 + col] = h;
        sY1l[y1b + row * 136 + col] = f2bf(v - bf2f(h));
      }
  }
  __syncthreads();

  // ---- E2: [16x128] @ W2^T -> out [16][12] ----
  {
    f32x4 a2 = {0.f, 0.f, 0.f, 0.f};
    #pragma unroll
    for (int kc = 0; kc < 4; ++kc) {
      short8 a2h = *(const short8*)&sY1h[y1b + lr * 136 + kc * 32 + lk];
      short8 a2l = *(const short8*)&sY1l[y1b + lr * 136 + kc * 32 + lk];
      short8 bh = *(const short8*)&sW2h[lr * 136 + kc * 32 + lk];
      short8 bo = *(const short8*)&sW2l[lr * 136 + kc * 32 + lk];
      a2 = __builtin_amdgcn_mfma_f32_16x16x32_bf16(a2h, bh, a2, 0, 0, 0);
      a2 = __builtin_amdgcn_mfma_f32_16x16x32_bf16(a2h, bo, a2, 0, 0, 0);
      a2 = __builtin_amdgcn_mfma_f32_16x16x32_bf16(a2l, bh, a2, 0, 0, 0);
    }
    int o = lr;
    if (o < 12) {
      float bv = b2[o];
      #pragma unroll
      for (int r = 0; r < 4; ++r) {
        int n = ntile + hk * 4 + r;
        if (n < NN)
          out[((size_t)(bb * NL + ll) * NN + n) * 12 + o] = a2[r] + bv;
      }
    }
  }
}

extern "C" void kernel_launch(void* const* d_in, const int* in_sizes, int n_in,
                              void* d_out, int out_size, void* d_ws, size_t ws_size,
                              hipStream_t stream) {
  (void)in_sizes; (void)n_in; (void)out_size; (void)ws_size;
  const float* x   = (const float*)d_in[0];
  const float* adj = (const float*)d_in[1];
  const float* wS  = (const float*)d_in[2];
  const float* bS  = (const float*)d_in[3];
  const float* G1  = (const float*)d_in[4];
  const float* bg1 = (const float*)d_in[5];
  const float* G2  = (const float*)d_in[6];
  const float* bg2 = (const float*)d_in[7];
  const float* we0 = (const float*)d_in[8];
  const float* be0 = (const float*)d_in[9];
  const float* we1 = (const float*)d_in[10];
  const float* be1 = (const float*)d_in[11];
  const float* we2 = (const float*)d_in[12];
  const float* be2 = (const float*)d_in[13];
  float* out = (float*)d_out;
  float* wsf = (float*)d_ws;

  float* rows = wsf + O_ROWS;
  float* cols = wsf + O_COLS;
  float* lnb  = wsf + O_LN;
  float* Cm   = wsf + O_CM;
  float* cvec = wsf + O_CV;

  unsigned short* M1h  = (unsigned short*)(wsf + R1);
  unsigned short* M1l  = (unsigned short*)(wsf + R1 + SZH);
  unsigned short* M2h  = (unsigned short*)(wsf + R1 + 2 * SZH);
  unsigned short* M2l  = (unsigned short*)(wsf + R1 + 3 * SZH);
  unsigned short* M1Th = (unsigned short*)(wsf + R2);
  unsigned short* M1Tl = (unsigned short*)(wsf + R2 + SZH);
  unsigned short* M2Th = (unsigned short*)(wsf + R2 + 2 * SZH);
  unsigned short* M2Tl = (unsigned short*)(wsf + R2 + 3 * SZH);
  unsigned short* T1h  = (unsigned short*)(wsf + R3);
  unsigned short* T1l  = (unsigned short*)(wsf + R3 + SZH);
  unsigned short* T2h  = (unsigned short*)(wsf + R3 + 2 * SZH);
  unsigned short* T2l  = (unsigned short*)(wsf + R3 + 3 * SZH);
  unsigned short* T1Th = M1Th;
  unsigned short* T1Tl = M1Tl;
  unsigned short* T2Th = M2Th;
  unsigned short* T2Tl = M2Tl;
  unsigned short* Phi  = (unsigned short*)(wsf + R1);
  unsigned short* Plo  = (unsigned short*)(wsf + R1 + 2 * SZH);
  float* X   = wsf + O_X;
  unsigned short* XTh = (unsigned short*)(wsf + O_XTH);
  unsigned short* XTl = (unsigned short*)(wsf + O_XTL);
  float* Yf  = wsf + O_YF;
  unsigned short* YTh = (unsigned short*)(wsf + O_YTH);
  unsigned short* YTl = (unsigned short*)(wsf + O_YTL);
  float* Zf  = wsf + O_ZF;
  float* H   = wsf + O_H;

  hipMemsetAsync(lnb, 0, 32 * sizeof(float), stream);
  k_rowsum<<<NN, 256, 0, stream>>>(adj, rows);
  k_colsum<<<32, 256, 0, stream>>>(adj, cols);
  k_buildM8<<<dim3(32, 32), 256, 0, stream>>>(adj, rows, cols,
      M1h, M1l, M2h, M2l, M1Th, M1Tl, M2Th, M2Tl);
  k_prep<<<1, 64, 0, stream>>>(wS, bS, G1, bg1, G2, bg2, Cm, cvec);

  // GEMM1: T1 = M1@M1, T2 = M2@M2
  {
    MG a0 = {M1h, M1l, M1Th, M1Tl, T1h, T1l, nullptr};
    MG a1 = {M2h, M2l, M2Th, M2Tl, T2h, T2l, nullptr};
    mgemm<128, 0><<<dim3(16, 16, 2), 256, 0, stream>>>(a0, a1, NP, NP, NP, NP);
  }
  k_transpose<<<dim3(32, 32, 4), 256, 0, stream>>>(T1h, T1Th);
  // GEMM2: P1 = T1@T1, P2 = T2@T2
  {
    MG b0 = {T1h, T1l, T1Th, T1Tl, Phi, Plo, nullptr};
    MG b1 = {T2h, T2l, T2Th, T2Tl, Phi + (size_t)NP * NP, Plo + (size_t)NP * NP, nullptr};
    mgemm<128, 0><<<dim3(16, 16, 2), 256, 0, stream>>>(b0, b1, NP, NP, NP, NP);
  }
  k_buildX<<<(NN * SW + 255) / 256, 256, 0, stream>>>(x, X);
  k_buildXT<<<(SW * NP + 255) / 256, 256, 0, stream>>>(x, XTh, XTl);
  // GEMM3: Yf = [P1;P2] @ X
  {
    MG c0 = {Phi, Plo, XTh, XTl, nullptr, nullptr, Yf};
    mgemm<64, 1><<<dim3(6, 32, 1), 256, 0, stream>>>(c0, c0, NP, NP, SW, NP);
  }
  k_reshapeYT<<<dim3(12, 32), 256, 0, stream>>>(Yf, YTh, YTl);
  // GEMM4: Zf = [P1;P2] @ [Y1|Y2]
  {
    MG e0 = {Phi, Plo, YTh, YTl, nullptr, nullptr, Zf};
    mgemm<64, 1><<<dim3(12, 32, 1), 256, 0, stream>>>(e0, e0, NP, NP, 768, NP);
  }

  k_combine<<<(NN * KW + 255) / 256, 256, 0, stream>>>(X, Yf, Zf, Cm, cvec, H);
  k_lnreduce<<<256, 256, 0, stream>>>(H, lnb);
  k_epilogue_mfma<<<dim3(32, NB * NL), 256, 0, stream>>>(
      H, lnb, we0, be0, we1, be1, we2, be2, out);
}